// Round 9
// baseline (172.060 us; speedup 1.0000x reference)
//
#include <hip/hip_runtime.h>
#include <math.h>

constexpr int NB = 8, NS = 2048, ND = 65;
constexpr int KP = 104;     // padded K stride for x conv (bf16): 208B, 16B-aligned, 2-way-free banks
constexpr int VD = 80;      // padded d rows for V^T
constexpr size_t OUTSZ = (size_t)NB * NS * ND;
constexpr size_t CONVN = (size_t)NB * NS * KP;   // x conv elems per array
constexpr size_t VTN   = (size_t)NB * VD * NS;   // V^T elems per array

typedef short short8 __attribute__((ext_vector_type(8)));
typedef float f32x4 __attribute__((ext_vector_type(4)));

union S8U { short8 v; ushort4 h[2]; };
__device__ __forceinline__ short8 ld_s8_2x8(const ushort* p) {
    // two 8B LDS loads (stride-68 rows are only 8B-aligned on odd rows)
    S8U u; u.h[0] = *(const ushort4*)p; u.h[1] = *(const ushort4*)(p + 4); return u.v;
}

__device__ __forceinline__ ushort f2bf(float f) {
    uint u = __float_as_uint(f);
    return (ushort)((u + 0x7fffu + ((u >> 16) & 1u)) >> 16);   // RNE
}
__device__ __forceinline__ float bf2f(ushort h) {
    return __uint_as_float((uint)h << 16);
}

// ---------------------------------------------------------------------------
// k0x: x fp32 -> (hi, lo) bf16 split arrays, K padded 65->104 with zeros.
// ---------------------------------------------------------------------------
__global__ __launch_bounds__(256)
void k0_convert(const float* __restrict__ x, ushort* __restrict__ xhi,
                ushort* __restrict__ xlo)
{
    size_t i = (size_t)blockIdx.x * 256 + threadIdx.x;
    if (i >= CONVN) return;
    int d = (int)(i % KP);
    size_t row = i / KP;
    ushort h = 0, l = 0;
    if (d < ND) {
        float v = x[row * ND + d];
        h = f2bf(v);
        l = f2bf(v - bf2f(h));
    }
    xhi[i] = h; xlo[i] = l;
}

// ---------------------------------------------------------------------------
// k0v: V [b,t,d] fp32 -> V^T hi/lo bf16 [b, d(80, zero-pad), t(2048)]
// ---------------------------------------------------------------------------
__global__ __launch_bounds__(256)
void k0v_transpose(const float* __restrict__ v, ushort* __restrict__ vthi,
                   ushort* __restrict__ vtlo)
{
    __shared__ float sT[128][66];
    const int tid = threadIdx.x, b = blockIdx.y, t0 = blockIdx.x * 128;
    const float* vb = v + (size_t)b * NS * ND;
    for (int i = tid; i < 128 * ND; i += 256) {
        int t = i / ND, d = i - t * ND;
        sT[t][d] = vb[(size_t)(t0 + t) * ND + d];
    }
    __syncthreads();
    for (int i = tid; i < VD * 128; i += 256) {
        int d = i >> 7, t = i & 127;
        float val = (d < ND) ? sT[t][d] : 0.0f;
        ushort h = f2bf(val);
        ushort l = f2bf(val - bf2f(h));
        size_t o = ((size_t)b * VD + d) * NS + t0 + t;
        vthi[o] = h; vtlo[o] = l;
    }
}

// ---------------------------------------------------------------------------
// k1_rowsum: per (batch, 32-row block): QK via split-bf16 MFMA, acosh->exp,
// rowsum ONLY (no E store). inv[row] -> ws. 512 thr (8 col-slab waves),
// TC=128, LDS 67.6 KB -> 2 blocks/CU, grid 512 -> 16 waves/CU.
// Per-16x16-tile math identical to k2's recompute => e bit-identical.
// ---------------------------------------------------------------------------
__global__ __launch_bounds__(512, 4)
void k1_rowsum(const ushort* __restrict__ xhi, const ushort* __restrict__ xlo,
               const float* __restrict__ tptr, float* __restrict__ invb)
{
    __shared__ __align__(16) ushort sAh[32 * KP], sAl[32 * KP];
    __shared__ __align__(16) ushort sBh[128 * KP], sBl[128 * KP];
    __shared__ float sSum[8][32];

    const int tid = threadIdx.x;
    const int b  = blockIdx.y;
    const int r0 = blockIdx.x * 32;
    const int lane = tid & 63;
    const int q = lane >> 4, c = lane & 15;
    const int wcs = tid >> 6;              // col-slab 0..7 (16 cols each)
    const float invT = 1.0f / (tptr[0] + 1e-8f);

    const ushort* xhb = xhi + (size_t)b * NS * KP;
    const ushort* xlb = xlo + (size_t)b * NS * KP;

    {   // stage A rows (32 x KP hi/lo)
        const uint4* gh = (const uint4*)(xhb + (size_t)r0 * KP);
        const uint4* gl = (const uint4*)(xlb + (size_t)r0 * KP);
        uint4* dh = (uint4*)sAh; uint4* dl = (uint4*)sAl;
        for (int i = tid; i < 32 * KP / 8; i += 512) { dh[i] = gh[i]; dl[i] = gl[i]; }
    }
    __syncthreads();
    if (tid < 32) { sAh[tid * KP] ^= 0x8000; sAl[tid * KP] ^= 0x8000; }  // negate time dim

    float rsum[2][4];
    #pragma unroll
    for (int rf = 0; rf < 2; ++rf)
        #pragma unroll
        for (int j = 0; j < 4; ++j) rsum[rf][j] = 0.0f;

    for (int tc = 0; tc < NS; tc += 128) {
        __syncthreads();
        {
            const uint4* gh = (const uint4*)(xhb + (size_t)tc * KP);
            const uint4* gl = (const uint4*)(xlb + (size_t)tc * KP);
            uint4* dh = (uint4*)sBh; uint4* dl = (uint4*)sBl;
            for (int i = tid; i < 128 * KP / 8; i += 512) { dh[i] = gh[i]; dl[i] = gl[i]; }
        }
        __syncthreads();

        f32x4 acc[2];
        #pragma unroll
        for (int rf = 0; rf < 2; ++rf)
            #pragma unroll
            for (int j = 0; j < 4; ++j) acc[rf][j] = 0.0f;

        #pragma unroll
        for (int kc = 0; kc < 3; ++kc) {
            const int koff = kc * 32 + q * 8;
            short8 bh = *(const short8*)&sBh[(wcs * 16 + c) * KP + koff];
            short8 bl = *(const short8*)&sBl[(wcs * 16 + c) * KP + koff];
            #pragma unroll
            for (int rf = 0; rf < 2; ++rf) {
                short8 ah = *(const short8*)&sAh[(rf * 16 + c) * KP + koff];
                short8 al = *(const short8*)&sAl[(rf * 16 + c) * KP + koff];
                acc[rf] = __builtin_amdgcn_mfma_f32_16x16x32_bf16(ah, bh, acc[rf], 0, 0, 0);
                acc[rf] = __builtin_amdgcn_mfma_f32_16x16x32_bf16(ah, bl, acc[rf], 0, 0, 0);
                acc[rf] = __builtin_amdgcn_mfma_f32_16x16x32_bf16(al, bh, acc[rf], 0, 0, 0);
            }
        }

        #pragma unroll
        for (int rf = 0; rf < 2; ++rf)
            #pragma unroll
            for (int j = 0; j < 4; ++j) {
                float z = -acc[rf][j];
                z = fminf(fmaxf(z, 1.0000001f), 50.0f);
                float dist = __logf(z + __fsqrt_rn(z * z - 1.0f));
                rsum[rf][j] += __expf(-dist * invT);
            }
    }

    // 16 lanes (c) share each row -> xor-reduce, then sum 8 col-slabs
    #pragma unroll
    for (int rf = 0; rf < 2; ++rf)
        #pragma unroll
        for (int j = 0; j < 4; ++j) {
            float v = rsum[rf][j];
            v += __shfl_xor(v, 1, 64);
            v += __shfl_xor(v, 2, 64);
            v += __shfl_xor(v, 4, 64);
            v += __shfl_xor(v, 8, 64);
            if (c == 0) sSum[wcs][rf * 16 + q * 4 + j] = v;
        }
    __syncthreads();
    if (tid < 32) {
        float s = 0.0f;
        #pragma unroll
        for (int k = 0; k < 8; ++k) s += sSum[k][tid];
        invb[(size_t)b * NS + r0 + tid] = 1.0f / s;
    }
}

// ---------------------------------------------------------------------------
// k2_attn_pv: per (batch, 32-row block), TC=64 chunks: recompute E (bit-
// identical tile math), en = e*inv in-register, write final attn ONCE,
// split en -> bf16 hi/lo into sP (stride 68 ushorts: j-grouped b16 stores
// hit disjoint bank octets -> conflict-free), PV 3-product MFMA vs LDS V^T.
// 8 waves: QK (wr2 x wc4); PV (wr2 x wk2 x fh2), wk halves reduced via sRed.
// LDS 63.1 KB -> 2 blocks/CU, grid 512. sP aliases sB; sRed aliases sV.
// ---------------------------------------------------------------------------
__global__ __launch_bounds__(512, 4)
void k2_attn_pv(const ushort* __restrict__ xhi, const ushort* __restrict__ xlo,
                const ushort* __restrict__ vthi, const ushort* __restrict__ vtlo,
                const float* __restrict__ tptr, const float* __restrict__ invb,
                float* __restrict__ attn, float* __restrict__ out)
{
    __shared__ __align__(16) char smem[63104];
    ushort* sAh = (ushort*)smem;               // 32*104  (6656 B)
    ushort* sAl = sAh + 32 * KP;               // 6656 B
    ushort* sBh = sAl + 32 * KP;               // 64*104  (13312 B)
    ushort* sBl = sBh + 64 * KP;               // 13312 B
    ushort* sVh = sBl + 64 * KP;               // 80*72   (11520 B)
    ushort* sVl = sVh + VD * 72;               // 11520 B
    float*  sInv = (float*)(sVl + VD * 72);    // 128 B
    ushort* sPh = sBh;                         // alias: 32*68 = 4352 B
    ushort* sPl = sBl;                         // alias
    float*  sRed = (float*)sVh;                // alias: 2*32*80*4 = 20480 B

    const int tid = threadIdx.x;
    const int b  = blockIdx.y;
    const int r0 = blockIdx.x * 32;
    const int lane = tid & 63;
    const int q = lane >> 4, c = lane & 15;
    const int w = tid >> 6;
    const int wr = w >> 2, wc = w & 3;          // QK: rows wr*16.., cols wc*16..
    const int wk = (w >> 1) & 1, fh = w & 1;    // PV: k-half, f-split
    const float invT = 1.0f / (tptr[0] + 1e-8f);

    const ushort* xhb = xhi + (size_t)b * NS * KP;
    const ushort* xlb = xlo + (size_t)b * NS * KP;
    const ushort* vh = vthi + (size_t)b * VD * NS;
    const ushort* vl = vtlo + (size_t)b * VD * NS;
    float* arow = attn + ((size_t)b * NS + r0) * NS;

    if (tid < 32) sInv[tid] = invb[(size_t)b * NS + r0 + tid];
    {   // stage A rows (32 x KP hi/lo)
        const uint4* gh = (const uint4*)(xhb + (size_t)r0 * KP);
        const uint4* gl = (const uint4*)(xlb + (size_t)r0 * KP);
        uint4* dh = (uint4*)sAh; uint4* dl = (uint4*)sAl;
        for (int i = tid; i < 32 * KP / 8; i += 512) { dh[i] = gh[i]; dl[i] = gl[i]; }
    }
    __syncthreads();
    if (tid < 32) { sAh[tid * KP] ^= 0x8000; sAl[tid * KP] ^= 0x8000; }  // negate time dim
    float rinv[4];
    #pragma unroll
    for (int j = 0; j < 4; ++j) rinv[j] = sInv[wr * 16 + q * 4 + j];

    const int f0 = fh ? 3 : 0;
    const int nf = fh ? 2 : 3;
    f32x4 oacc[3];
    #pragma unroll
    for (int f = 0; f < 3; ++f)
        #pragma unroll
        for (int j = 0; j < 4; ++j) oacc[f][j] = 0.0f;

    for (int tc = 0; tc < NS; tc += 64) {
        __syncthreads();   // prev PV done reading sP/sV; first iter: A/Inv phase done
        {   // stage B tile (64 x KP hi/lo)
            const uint4* gh = (const uint4*)(xhb + (size_t)tc * KP);
            const uint4* gl = (const uint4*)(xlb + (size_t)tc * KP);
            uint4* dh = (uint4*)sBh; uint4* dl = (uint4*)sBl;
            for (int i = tid; i < 64 * KP / 8; i += 512) { dh[i] = gh[i]; dl[i] = gl[i]; }
        }
        {   // stage V^T chunk [80][64] hi/lo, stride 72
            for (int i = tid; i < VD * 8; i += 512) {
                int d = i >> 3, c8 = i & 7;
                size_t go = (size_t)d * NS + tc + c8 * 8;
                *(short8*)&sVh[d * 72 + c8 * 8] = *(const short8*)&vh[go];
                *(short8*)&sVl[d * 72 + c8 * 8] = *(const short8*)&vl[go];
            }
        }
        __syncthreads();

        // ---- QK: one 16x16 tile per wave ----
        f32x4 acc;
        #pragma unroll
        for (int j = 0; j < 4; ++j) acc[j] = 0.0f;
        #pragma unroll
        for (int kc = 0; kc < 3; ++kc) {
            const int koff = kc * 32 + q * 8;
            short8 ah = *(const short8*)&sAh[(wr * 16 + c) * KP + koff];
            short8 al = *(const short8*)&sAl[(wr * 16 + c) * KP + koff];
            short8 bh = *(const short8*)&sBh[(wc * 16 + c) * KP + koff];
            short8 bl = *(const short8*)&sBl[(wc * 16 + c) * KP + koff];
            acc = __builtin_amdgcn_mfma_f32_16x16x32_bf16(ah, bh, acc, 0, 0, 0);
            acc = __builtin_amdgcn_mfma_f32_16x16x32_bf16(ah, bl, acc, 0, 0, 0);
            acc = __builtin_amdgcn_mfma_f32_16x16x32_bf16(al, bh, acc, 0, 0, 0);
        }
        __syncthreads();   // sB reads done -> sP alias writes safe

        // ---- epilogue: e (bit-identical to k1), normalize, store, split ----
        #pragma unroll
        for (int j = 0; j < 4; ++j) {
            float z = -acc[j];
            z = fminf(fmaxf(z, 1.0000001f), 50.0f);
            float dist = __logf(z + __fsqrt_rn(z * z - 1.0f));
            float en = __expf(-dist * invT) * rinv[j];
            int row = wr * 16 + q * 4 + j;
            int col = wc * 16 + c;
            arow[(size_t)row * NS + tc + col] = en;
            ushort h = f2bf(en);
            sPh[row * 68 + col] = h;
            sPl[row * 68 + col] = f2bf(en - bf2f(h));
        }
        __syncthreads();   // sP visible

        // ---- PV: A = P (rows wr*16.., k = wk*32..), B = V^T ----
        {
            const int pb = (wr * 16 + c) * 68 + wk * 32 + q * 8;
            short8 ph = ld_s8_2x8(&sPh[pb]);
            short8 pl = ld_s8_2x8(&sPl[pb]);
            #pragma unroll
            for (int ff = 0; ff < 3; ++ff) {
                if (ff >= nf) break;
                const int vo = ((f0 + ff) * 16 + c) * 72 + wk * 32 + q * 8;
                short8 bh = *(const short8*)&sVh[vo];
                short8 bl = *(const short8*)&sVl[vo];
                oacc[ff] = __builtin_amdgcn_mfma_f32_16x16x32_bf16(ph, bh, oacc[ff], 0, 0, 0);
                oacc[ff] = __builtin_amdgcn_mfma_f32_16x16x32_bf16(ph, bl, oacc[ff], 0, 0, 0);
                oacc[ff] = __builtin_amdgcn_mfma_f32_16x16x32_bf16(pl, bh, oacc[ff], 0, 0, 0);
            }
        }
    }

    __syncthreads();   // last PV done -> sV region reusable as sRed
    #pragma unroll
    for (int ff = 0; ff < 3; ++ff) {
        if (ff >= nf) break;
        #pragma unroll
        for (int j = 0; j < 4; ++j) {
            int r = wr * 16 + q * 4 + j;
            int d = (f0 + ff) * 16 + c;
            sRed[(size_t)(wk * 32 + r) * VD + d] = oacc[ff][j];
        }
    }
    __syncthreads();
    for (int i = tid; i < 32 * VD; i += 512) {
        int r = i / VD, d = i - r * VD;
        float s = sRed[i] + sRed[32 * VD + i];
        if (d < ND) out[((size_t)b * NS + r0 + r) * ND + d] = s;
    }
}

extern "C" void kernel_launch(void* const* d_in, const int* in_sizes, int n_in,
                              void* d_out, int out_size, void* d_ws, size_t ws_size,
                              hipStream_t stream) {
    const float* x      = (const float*)d_in[0];
    const float* values = (const float*)d_in[1];
    const float* temp   = (const float*)d_in[2];

    float* out  = (float*)d_out;
    float* attn = out + OUTSZ;

    // ws: xhi/xlo 6.8 MB + vt 5.24 MB + invb 64 KB = 12.1 MB (proven >=17 MB)
    ushort* xhi  = (ushort*)d_ws;
    ushort* xlo  = xhi + CONVN;
    ushort* vthi = xlo + CONVN;
    ushort* vtlo = vthi + VTN;
    float*  invb = (float*)(vtlo + VTN);

    k0_convert<<<(int)((CONVN + 255) / 256), 256, 0, stream>>>(x, xhi, xlo);
    k0v_transpose<<<dim3(NS / 128, NB), 256, 0, stream>>>(values, vthi, vtlo);

    k1_rowsum<<<dim3(NS / 32, NB), 512, 0, stream>>>(xhi, xlo, temp, invb);
    k2_attn_pv<<<dim3(NS / 32, NB), 512, 0, stream>>>(xhi, xlo, vthi, vtlo,
                                                      temp, invb, attn, out);
}

// Round 10
// 128.712 us; speedup vs baseline: 1.3368x; 1.3368x over previous
//
#include <hip/hip_runtime.h>
#include <math.h>

constexpr int NB = 8, NS = 2048, ND = 65;
constexpr int KP = 104;     // padded K stride for x conv (bf16 elems)
constexpr int VD = 80;      // padded d rows for V^T
constexpr size_t OUTSZ = (size_t)NB * NS * ND;
constexpr size_t CONVN = (size_t)NB * NS * KP;   // x conv elems per array
constexpr size_t VTN   = (size_t)NB * VD * NS;   // V^T elems per array

typedef short short8 __attribute__((ext_vector_type(8)));
typedef float f32x4 __attribute__((ext_vector_type(4)));

__device__ __forceinline__ ushort f2bf(float f) {
    uint u = __float_as_uint(f);
    return (ushort)((u + 0x7fffu + ((u >> 16) & 1u)) >> 16);   // RNE
}
__device__ __forceinline__ float bf2f(ushort h) {
    return __uint_as_float((uint)h << 16);
}

// ---------------------------------------------------------------------------
// k0x: x fp32 -> (hi, lo) bf16 split arrays, K padded 65->104 with zeros.
// ---------------------------------------------------------------------------
__global__ __launch_bounds__(256)
void k0_convert(const float* __restrict__ x, ushort* __restrict__ xhi,
                ushort* __restrict__ xlo)
{
    size_t i = (size_t)blockIdx.x * 256 + threadIdx.x;
    if (i >= CONVN) return;
    int d = (int)(i % KP);
    size_t row = i / KP;
    ushort h = 0, l = 0;
    if (d < ND) {
        float v = x[row * ND + d];
        h = f2bf(v);
        l = f2bf(v - bf2f(h));
    }
    xhi[i] = h; xlo[i] = l;
}

// ---------------------------------------------------------------------------
// k0v: V [b,t,d] fp32 -> V^T hi/lo bf16 [b, d(80, zero-pad), t(2048)]
// 32-row t-chunks -> 512 blocks (2/CU) instead of 128 (0.5/CU).
// ---------------------------------------------------------------------------
__global__ __launch_bounds__(256)
void k0v_transpose(const float* __restrict__ v, ushort* __restrict__ vthi,
                   ushort* __restrict__ vtlo)
{
    __shared__ float sT[32][66];
    const int tid = threadIdx.x, b = blockIdx.y, t0 = blockIdx.x * 32;
    const float* vb = v + (size_t)b * NS * ND;
    for (int i = tid; i < 32 * ND; i += 256) {
        int t = i / ND, d = i - t * ND;
        sT[t][d] = vb[(size_t)(t0 + t) * ND + d];
    }
    __syncthreads();
    for (int i = tid; i < VD * 32; i += 256) {
        int d = i >> 5, t = i & 31;
        float val = (d < ND) ? sT[t][d] : 0.0f;
        ushort h = f2bf(val);
        ushort l = f2bf(val - bf2f(h));
        size_t o = ((size_t)b * VD + d) * NS + t0 + t;
        vthi[o] = h; vtlo[o] = l;
    }
}

// ---------------------------------------------------------------------------
// k1: per (batch, 64-row block): S via split-bf16 MFMA (hi*hi+hi*lo+lo*hi),
// E = exp(-acosh(clip)/T) written fp32 unnormalized, inv[row] -> ws.
// TC=128 single-buffered: LDS 79 KB -> 2 blocks/CU (16 waves) to hide
// barrier drains. XCD-swizzled 1D grid: each XCD owns one batch, so the
// batch's B-panels (1.7 MB hi+lo) stay L2-resident (was 84 MB FETCH).
// Scores in [-4.61, -4.5e-4] => exp without max-subtract == softmax exactly.
// ---------------------------------------------------------------------------
__global__ __launch_bounds__(512, 4)
void k1_scores(const ushort* __restrict__ xhi, const ushort* __restrict__ xlo,
               const float* __restrict__ tptr, float* __restrict__ attn,
               float* __restrict__ invb)
{
    __shared__ __align__(16) ushort sAh[64 * KP], sAl[64 * KP];
    __shared__ __align__(16) ushort sBh[128 * KP], sBl[128 * KP];
    __shared__ float sSum[4][64];

    const int tid = threadIdx.x;
    // XCD swizzle: dispatch d -> logical f = (d%8)*32 + d/8 (bijective, 256%8==0)
    const int f  = (blockIdx.x & 7) * 32 + (blockIdx.x >> 3);
    const int b  = f >> 5;
    const int r0 = (f & 31) * 64;
    const int lane = tid & 63;
    const int w  = tid >> 6;
    const int wr = w >> 2;          // 0..1  (32-row slab)
    const int wc = w & 3;           // 0..3  (32-col slab)
    const float invT = 1.0f / (tptr[0] + 1e-8f);

    const ushort* xhb = xhi + (size_t)b * NS * KP;
    const ushort* xlb = xlo + (size_t)b * NS * KP;
    float* arow = attn + ((size_t)b * NS + r0) * NS;

    {
        const uint4* sh = (const uint4*)(xhb + (size_t)r0 * KP);
        const uint4* sl = (const uint4*)(xlb + (size_t)r0 * KP);
        uint4* dh = (uint4*)sAh; uint4* dl = (uint4*)sAl;
        for (int i = tid; i < 64 * KP / 8; i += 512) { dh[i] = sh[i]; dl[i] = sl[i]; }
    }
    __syncthreads();
    if (tid < 64) { sAh[tid * KP] ^= 0x8000; sAl[tid * KP] ^= 0x8000; }  // negate time dim

    float rsum[2][4];
    #pragma unroll
    for (int rf = 0; rf < 2; ++rf)
        #pragma unroll
        for (int j = 0; j < 4; ++j) rsum[rf][j] = 0.0f;

    for (int tc = 0; tc < NS; tc += 128) {
        __syncthreads();
        {
            const uint4* gh = (const uint4*)(xhb + (size_t)tc * KP);
            const uint4* gl = (const uint4*)(xlb + (size_t)tc * KP);
            uint4* dh = (uint4*)sBh; uint4* dl = (uint4*)sBl;
            for (int i = tid; i < 128 * KP / 8; i += 512) { dh[i] = gh[i]; dl[i] = gl[i]; }
        }
        __syncthreads();

        f32x4 acc[2][2];
        #pragma unroll
        for (int rf = 0; rf < 2; ++rf)
            #pragma unroll
            for (int cf = 0; cf < 2; ++cf)
                #pragma unroll
                for (int j = 0; j < 4; ++j) acc[rf][cf][j] = 0.0f;

        #pragma unroll
        for (int kc = 0; kc < 3; ++kc) {
            const int koff = kc * 32 + (lane >> 4) * 8;
            short8 ah[2], al[2], bh[2], bl[2];
            #pragma unroll
            for (int rf = 0; rf < 2; ++rf) {
                int ro = (wr * 32 + rf * 16 + (lane & 15)) * KP + koff;
                ah[rf] = *(const short8*)&sAh[ro];
                al[rf] = *(const short8*)&sAl[ro];
            }
            #pragma unroll
            for (int cf = 0; cf < 2; ++cf) {
                int co = (wc * 32 + cf * 16 + (lane & 15)) * KP + koff;
                bh[cf] = *(const short8*)&sBh[co];
                bl[cf] = *(const short8*)&sBl[co];
            }
            #pragma unroll
            for (int rf = 0; rf < 2; ++rf)
                #pragma unroll
                for (int cf = 0; cf < 2; ++cf) {
                    acc[rf][cf] = __builtin_amdgcn_mfma_f32_16x16x32_bf16(ah[rf], bh[cf], acc[rf][cf], 0, 0, 0);
                    acc[rf][cf] = __builtin_amdgcn_mfma_f32_16x16x32_bf16(ah[rf], bl[cf], acc[rf][cf], 0, 0, 0);
                    acc[rf][cf] = __builtin_amdgcn_mfma_f32_16x16x32_bf16(al[rf], bh[cf], acc[rf][cf], 0, 0, 0);
                }
        }

        // epilogue: compute all e first, then line-adjacent stores (cf inner)
        float ev[2][2][4];
        #pragma unroll
        for (int rf = 0; rf < 2; ++rf)
            #pragma unroll
            for (int cf = 0; cf < 2; ++cf)
                #pragma unroll
                for (int j = 0; j < 4; ++j) {
                    float z = -acc[rf][cf][j];
                    z = fminf(fmaxf(z, 1.0000001f), 50.0f);
                    float dist = __logf(z + __fsqrt_rn(z * z - 1.0f));
                    float e = __expf(-dist * invT);
                    ev[rf][cf][j] = e;
                    rsum[rf][j] += e;
                }
        #pragma unroll
        for (int rf = 0; rf < 2; ++rf)
            #pragma unroll
            for (int j = 0; j < 4; ++j) {
                int row = wr * 32 + rf * 16 + (lane >> 4) * 4 + j;
                #pragma unroll
                for (int cf = 0; cf < 2; ++cf) {
                    int col = tc + wc * 32 + cf * 16 + (lane & 15);
                    arow[(size_t)row * NS + col] = ev[rf][cf][j];
                }
            }
    }

    // deterministic row-sum reduce: 16 lanes (lane&15) share each row
    #pragma unroll
    for (int rf = 0; rf < 2; ++rf)
        #pragma unroll
        for (int j = 0; j < 4; ++j) {
            float v = rsum[rf][j];
            v += __shfl_xor(v, 1, 64);
            v += __shfl_xor(v, 2, 64);
            v += __shfl_xor(v, 4, 64);
            v += __shfl_xor(v, 8, 64);
            if ((lane & 15) == 0)
                sSum[wc][wr * 32 + rf * 16 + (lane >> 4) * 4 + j] = v;
        }
    __syncthreads();
    if (tid < 64)
        invb[(size_t)b * NS + r0 + tid] =
            1.0f / (sSum[0][tid] + sSum[1][tid] + sSum[2][tid] + sSum[3][tid]);
}

// ---------------------------------------------------------------------------
// k2 (r6-proven, ~60us): per (batch, 32-row block): read E tile (L3-hot),
// normalize, write attn in place, split to bf16 in LDS; stage V^T chunk
// [80][128] hi/lo into LDS (coalesced), MFMA PV, 4 waves k-slicing; partial O
// reduced via LDS buffer aliasing the dead sV region (2 blocks/CU).
// XCD-swizzled 1D grid (512%8==0): V^T per batch stays L2-resident.
// ---------------------------------------------------------------------------
__global__ __launch_bounds__(256, 2)
void k2_pv(float* __restrict__ attn, const ushort* __restrict__ vthi,
           const ushort* __restrict__ vtlo, const float* __restrict__ invb,
           float* __restrict__ out)
{
    __shared__ __align__(16) char smem[(32 * 136 * 2 + 80 * 136 * 2) * 2];
    ushort* sAh = (ushort*)smem;            // 32*136
    ushort* sAl = sAh + 32 * 136;
    ushort* sVh = sAl + 32 * 136;           // 80*136
    ushort* sVl = sVh + 80 * 136;
    float*  sRed = (float*)(sAl + 32 * 136);   // 4*32*80 f32 aliases sV
    __shared__ float sInvL[32];

    const int tid = threadIdx.x;
    // XCD swizzle: dispatch d -> logical f = (d%8)*64 + d/8 (bijective, 512%8==0)
    const int f  = (blockIdx.x & 7) * 64 + (blockIdx.x >> 3);
    const int b  = f >> 6;
    const int r0 = (f & 63) * 32;
    const int lane = tid & 63;
    const int wk = tid >> 6;          // k-slice 0..3 within each 128-chunk

    if (tid < 32) sInvL[tid] = invb[(size_t)b * NS + r0 + tid];

    float* arow = attn + ((size_t)b * NS + r0) * NS;
    const ushort* vh = vthi + (size_t)b * VD * NS;
    const ushort* vl = vtlo + (size_t)b * VD * NS;

    f32x4 acc[2][5];
    #pragma unroll
    for (int rf = 0; rf < 2; ++rf)
        #pragma unroll
        for (int ff = 0; ff < 5; ++ff)
            #pragma unroll
            for (int j = 0; j < 4; ++j) acc[rf][ff][j] = 0.0f;

    __syncthreads();

    for (int kt = 0; kt < NS; kt += 128) {
        // stage E: 32 rows x 32 float4; RMW normalize + bf16 split into sA
        #pragma unroll
        for (int rep = 0; rep < 4; ++rep) {
            int idx = tid + rep * 256;
            int row = idx >> 5, c4 = idx & 31;
            float4* p = (float4*)&arow[(size_t)row * NS + kt + c4 * 4];
            float4 e = *p;
            float inv = sInvL[row];
            e.x *= inv; e.y *= inv; e.z *= inv; e.w *= inv;
            *p = e;
            ushort h0 = f2bf(e.x), h1 = f2bf(e.y), h2 = f2bf(e.z), h3 = f2bf(e.w);
            ushort l0 = f2bf(e.x - bf2f(h0)), l1 = f2bf(e.y - bf2f(h1));
            ushort l2 = f2bf(e.z - bf2f(h2)), l3 = f2bf(e.w - bf2f(h3));
            int so = row * 136 + c4 * 4;
            *(ushort4*)&sAh[so] = make_ushort4(h0, h1, h2, h3);
            *(ushort4*)&sAl[so] = make_ushort4(l0, l1, l2, l3);
        }
        // stage V^T chunk [80][128] hi/lo: coalesced 16B/lane rows
        #pragma unroll
        for (int rep = 0; rep < 5; ++rep) {
            int i = tid + rep * 256;
            int d = i >> 4, c8 = i & 15;
            size_t go = (size_t)d * NS + kt + c8 * 8;
            *(short8*)&sVh[d * 136 + c8 * 8] = *(const short8*)&vh[go];
            *(short8*)&sVl[d * 136 + c8 * 8] = *(const short8*)&vl[go];
        }
        __syncthreads();

        const int koff = wk * 32 + (lane >> 4) * 8;
        short8 ah[2], al[2];
        #pragma unroll
        for (int rf = 0; rf < 2; ++rf) {
            int ro = (rf * 16 + (lane & 15)) * 136 + koff;
            ah[rf] = *(const short8*)&sAh[ro];
            al[rf] = *(const short8*)&sAl[ro];
        }
        #pragma unroll
        for (int ff = 0; ff < 5; ++ff) {
            int vo = (ff * 16 + (lane & 15)) * 136 + koff;
            short8 bh = *(const short8*)&sVh[vo];
            short8 bl = *(const short8*)&sVl[vo];
            #pragma unroll
            for (int rf = 0; rf < 2; ++rf) {
                acc[rf][ff] = __builtin_amdgcn_mfma_f32_16x16x32_bf16(ah[rf], bh, acc[rf][ff], 0, 0, 0);
                acc[rf][ff] = __builtin_amdgcn_mfma_f32_16x16x32_bf16(ah[rf], bl, acc[rf][ff], 0, 0, 0);
                acc[rf][ff] = __builtin_amdgcn_mfma_f32_16x16x32_bf16(al[rf], bh, acc[rf][ff], 0, 0, 0);
            }
        }
        __syncthreads();   // protect sA/sV rewrite next chunk
    }

    // write k-slice partials into sRed (aliases dead sV region)
    #pragma unroll
    for (int rf = 0; rf < 2; ++rf)
        #pragma unroll
        for (int ff = 0; ff < 5; ++ff)
            #pragma unroll
            for (int j = 0; j < 4; ++j) {
                int r = rf * 16 + (lane >> 4) * 4 + j;
                int d = ff * 16 + (lane & 15);
                sRed[((size_t)wk * 32 + r) * 80 + d] = acc[rf][ff][j];
            }
    __syncthreads();
    for (int i = tid; i < 32 * 80; i += 256) {
        int r = i / 80, d = i - r * 80;
        float s = sRed[(size_t)r * 80 + d] + sRed[(size_t)(32 + r) * 80 + d]
                + sRed[(size_t)(64 + r) * 80 + d] + sRed[(size_t)(96 + r) * 80 + d];
        if (d < ND) out[((size_t)b * NS + r0 + r) * ND + d] = s;
    }
}

extern "C" void kernel_launch(void* const* d_in, const int* in_sizes, int n_in,
                              void* d_out, int out_size, void* d_ws, size_t ws_size,
                              hipStream_t stream) {
    const float* x      = (const float*)d_in[0];
    const float* values = (const float*)d_in[1];
    const float* temp   = (const float*)d_in[2];

    float* out  = (float*)d_out;
    float* attn = out + OUTSZ;

    ushort* xhi  = (ushort*)d_ws;
    ushort* xlo  = xhi + CONVN;
    ushort* vthi = xlo + CONVN;
    ushort* vtlo = vthi + VTN;
    float*  invb = (float*)(vtlo + VTN);

    k0_convert<<<(int)((CONVN + 255) / 256), 256, 0, stream>>>(x, xhi, xlo);
    k0v_transpose<<<dim3(NS / 32, NB), 256, 0, stream>>>(values, vthi, vtlo);

    k1_scores<<<256, 512, 0, stream>>>(xhi, xlo, temp, attn, invb);
    k2_pv<<<512, 256, 0, stream>>>(attn, vthi, vtlo, invb, out);
}

// Round 11
// 122.810 us; speedup vs baseline: 1.4010x; 1.0481x over previous
//
#include <hip/hip_runtime.h>
#include <math.h>

constexpr int NB = 8, NS = 2048, ND = 65;
constexpr int KP = 104;     // padded K stride for x conv (bf16 elems)
constexpr int VD = 80;      // padded d rows for V^T
constexpr size_t OUTSZ = (size_t)NB * NS * ND;
constexpr size_t CONVN = (size_t)NB * NS * KP;   // x conv elems per array
constexpr size_t VTN   = (size_t)NB * VD * NS;   // V^T elems per array

typedef short short8 __attribute__((ext_vector_type(8)));
typedef float f32x4 __attribute__((ext_vector_type(4)));

__device__ __forceinline__ ushort f2bf(float f) {
    uint u = __float_as_uint(f);
    return (ushort)((u + 0x7fffu + ((u >> 16) & 1u)) >> 16);   // RNE
}
__device__ __forceinline__ float bf2f(ushort h) {
    return __uint_as_float((uint)h << 16);
}

// ---------------------------------------------------------------------------
// k0x: x fp32 -> (hi, lo) bf16 split arrays, K padded 65->104 with zeros.
// ---------------------------------------------------------------------------
__global__ __launch_bounds__(256)
void k0_convert(const float* __restrict__ x, ushort* __restrict__ xhi,
                ushort* __restrict__ xlo)
{
    size_t i = (size_t)blockIdx.x * 256 + threadIdx.x;
    if (i >= CONVN) return;
    int d = (int)(i % KP);
    size_t row = i / KP;
    ushort h = 0, l = 0;
    if (d < ND) {
        float v = x[row * ND + d];
        h = f2bf(v);
        l = f2bf(v - bf2f(h));
    }
    xhi[i] = h; xlo[i] = l;
}

// ---------------------------------------------------------------------------
// k0v: V [b,t,d] fp32 -> V^T hi/lo bf16 [b, d(80, zero-pad), t(2048)]
// ---------------------------------------------------------------------------
__global__ __launch_bounds__(256)
void k0v_transpose(const float* __restrict__ v, ushort* __restrict__ vthi,
                   ushort* __restrict__ vtlo)
{
    __shared__ float sT[32][66];
    const int tid = threadIdx.x, b = blockIdx.y, t0 = blockIdx.x * 32;
    const float* vb = v + (size_t)b * NS * ND;
    for (int i = tid; i < 32 * ND; i += 256) {
        int t = i / ND, d = i - t * ND;
        sT[t][d] = vb[(size_t)(t0 + t) * ND + d];
    }
    __syncthreads();
    for (int i = tid; i < VD * 32; i += 256) {
        int d = i >> 5, t = i & 31;
        float val = (d < ND) ? sT[t][d] : 0.0f;
        ushort h = f2bf(val);
        ushort l = f2bf(val - bf2f(h));
        size_t o = ((size_t)b * VD + d) * NS + t0 + t;
        vthi[o] = h; vtlo[o] = l;
    }
}

// ---------------------------------------------------------------------------
// k1: per (batch, 64-row block): S via split-bf16 MFMA (hi*hi+hi*lo+lo*hi),
// E = exp(-acosh(clip)/T) written fp32 unnormalized, inv[row] -> ws.
// TC=128, 2 blocks/CU, XCD-swizzled grid (batch per XCD -> B-panels L2-hot).
// Fast path: fp32 (T+1e-8)==1.0 => invT==1 => E = rcp(z+sqrt(z^2-1))
// (exp(-acosh(z)) = 1/w). Uniform branch; general exp/log path kept.
// ---------------------------------------------------------------------------
__global__ __launch_bounds__(512, 4)
void k1_scores(const ushort* __restrict__ xhi, const ushort* __restrict__ xlo,
               const float* __restrict__ tptr, float* __restrict__ attn,
               float* __restrict__ invb)
{
    __shared__ __align__(16) ushort sAh[64 * KP], sAl[64 * KP];
    __shared__ __align__(16) ushort sBh[128 * KP], sBl[128 * KP];
    __shared__ float sSum[4][64];

    const int tid = threadIdx.x;
    // XCD swizzle: dispatch d -> logical f = (d%8)*32 + d/8 (bijective, 256%8==0)
    const int f  = (blockIdx.x & 7) * 32 + (blockIdx.x >> 3);
    const int b  = f >> 5;
    const int r0 = (f & 31) * 64;
    const int lane = tid & 63;
    const int w  = tid >> 6;
    const int wr = w >> 2;          // 0..1  (32-row slab)
    const int wc = w & 3;           // 0..3  (32-col slab)
    const float invT = 1.0f / (tptr[0] + 1e-8f);
    const bool fastT = (invT == 1.0f);

    const ushort* xhb = xhi + (size_t)b * NS * KP;
    const ushort* xlb = xlo + (size_t)b * NS * KP;
    float* arow = attn + ((size_t)b * NS + r0) * NS;

    {
        const uint4* sh = (const uint4*)(xhb + (size_t)r0 * KP);
        const uint4* sl = (const uint4*)(xlb + (size_t)r0 * KP);
        uint4* dh = (uint4*)sAh; uint4* dl = (uint4*)sAl;
        for (int i = tid; i < 64 * KP / 8; i += 512) { dh[i] = sh[i]; dl[i] = sl[i]; }
    }
    __syncthreads();
    if (tid < 64) { sAh[tid * KP] ^= 0x8000; sAl[tid * KP] ^= 0x8000; }  // negate time dim

    float rsum[2][4];
    #pragma unroll
    for (int rf = 0; rf < 2; ++rf)
        #pragma unroll
        for (int j = 0; j < 4; ++j) rsum[rf][j] = 0.0f;

    for (int tc = 0; tc < NS; tc += 128) {
        __syncthreads();
        {
            const uint4* gh = (const uint4*)(xhb + (size_t)tc * KP);
            const uint4* gl = (const uint4*)(xlb + (size_t)tc * KP);
            uint4* dh = (uint4*)sBh; uint4* dl = (uint4*)sBl;
            for (int i = tid; i < 128 * KP / 8; i += 512) { dh[i] = gh[i]; dl[i] = gl[i]; }
        }
        __syncthreads();

        f32x4 acc[2][2];
        #pragma unroll
        for (int rf = 0; rf < 2; ++rf)
            #pragma unroll
            for (int cf = 0; cf < 2; ++cf)
                #pragma unroll
                for (int j = 0; j < 4; ++j) acc[rf][cf][j] = 0.0f;

        #pragma unroll
        for (int kc = 0; kc < 3; ++kc) {
            const int koff = kc * 32 + (lane >> 4) * 8;
            short8 ah[2], al[2], bh[2], bl[2];
            #pragma unroll
            for (int rf = 0; rf < 2; ++rf) {
                int ro = (wr * 32 + rf * 16 + (lane & 15)) * KP + koff;
                ah[rf] = *(const short8*)&sAh[ro];
                al[rf] = *(const short8*)&sAl[ro];
            }
            #pragma unroll
            for (int cf = 0; cf < 2; ++cf) {
                int co = (wc * 32 + cf * 16 + (lane & 15)) * KP + koff;
                bh[cf] = *(const short8*)&sBh[co];
                bl[cf] = *(const short8*)&sBl[co];
            }
            #pragma unroll
            for (int rf = 0; rf < 2; ++rf)
                #pragma unroll
                for (int cf = 0; cf < 2; ++cf) {
                    acc[rf][cf] = __builtin_amdgcn_mfma_f32_16x16x32_bf16(ah[rf], bh[cf], acc[rf][cf], 0, 0, 0);
                    acc[rf][cf] = __builtin_amdgcn_mfma_f32_16x16x32_bf16(ah[rf], bl[cf], acc[rf][cf], 0, 0, 0);
                    acc[rf][cf] = __builtin_amdgcn_mfma_f32_16x16x32_bf16(al[rf], bh[cf], acc[rf][cf], 0, 0, 0);
                }
        }

        // epilogue: compute all e first, then line-adjacent stores (cf inner)
        float ev[2][2][4];
        #pragma unroll
        for (int rf = 0; rf < 2; ++rf)
            #pragma unroll
            for (int cf = 0; cf < 2; ++cf)
                #pragma unroll
                for (int j = 0; j < 4; ++j) {
                    float z = -acc[rf][cf][j];
                    z = fminf(fmaxf(z, 1.0000001f), 50.0f);
                    float w2 = z + __fsqrt_rn(z * z - 1.0f);
                    float e = fastT ? __builtin_amdgcn_rcpf(w2)
                                    : __expf(-__logf(w2) * invT);
                    ev[rf][cf][j] = e;
                    rsum[rf][j] += e;
                }
        #pragma unroll
        for (int rf = 0; rf < 2; ++rf)
            #pragma unroll
            for (int j = 0; j < 4; ++j) {
                int row = wr * 32 + rf * 16 + (lane >> 4) * 4 + j;
                #pragma unroll
                for (int cf = 0; cf < 2; ++cf) {
                    int col = tc + wc * 32 + cf * 16 + (lane & 15);
                    arow[(size_t)row * NS + col] = ev[rf][cf][j];
                }
            }
    }

    // deterministic row-sum reduce: 16 lanes (lane&15) share each row
    #pragma unroll
    for (int rf = 0; rf < 2; ++rf)
        #pragma unroll
        for (int j = 0; j < 4; ++j) {
            float v = rsum[rf][j];
            v += __shfl_xor(v, 1, 64);
            v += __shfl_xor(v, 2, 64);
            v += __shfl_xor(v, 4, 64);
            v += __shfl_xor(v, 8, 64);
            if ((lane & 15) == 0)
                sSum[wc][wr * 32 + rf * 16 + (lane >> 4) * 4 + j] = v;
        }
    __syncthreads();
    if (tid < 64)
        invb[(size_t)b * NS + r0 + tid] =
            1.0f / (sSum[0][tid] + sSum[1][tid] + sSum[2][tid] + sSum[3][tid]);
}

// ---------------------------------------------------------------------------
// k2: per (batch, 32-row block): T14 async-stage — E tile (L3-hot) and V^T
// chunk prefetched into REGISTERS one chunk ahead (issued right after the
// barrier, drain during MFMA); phase 1 is pure stores: normalize ereg,
// write attn, bf16-split to sA, ds_write vreg->sV. MFMA PV, 4 waves k-slice;
// partials reduced via LDS aliasing dead sV. XCD-swizzled grid.
// ---------------------------------------------------------------------------
__global__ __launch_bounds__(256, 2)
void k2_pv(float* __restrict__ attn, const ushort* __restrict__ vthi,
           const ushort* __restrict__ vtlo, const float* __restrict__ invb,
           float* __restrict__ out)
{
    __shared__ __align__(16) char smem[(32 * 136 * 2 + 80 * 136 * 2) * 2];
    ushort* sAh = (ushort*)smem;            // 32*136
    ushort* sAl = sAh + 32 * 136;
    ushort* sVh = sAl + 32 * 136;           // 80*136
    ushort* sVl = sVh + 80 * 136;
    float*  sRed = (float*)(sAl + 32 * 136);   // 4*32*80 f32 aliases sV
    __shared__ float sInvL[32];

    const int tid = threadIdx.x;
    // XCD swizzle: dispatch d -> logical f = (d%8)*64 + d/8 (bijective, 512%8==0)
    const int f  = (blockIdx.x & 7) * 64 + (blockIdx.x >> 3);
    const int b  = f >> 6;
    const int r0 = (f & 63) * 32;
    const int lane = tid & 63;
    const int wk = tid >> 6;          // k-slice 0..3 within each 128-chunk

    if (tid < 32) sInvL[tid] = invb[(size_t)b * NS + r0 + tid];

    float* arow = attn + ((size_t)b * NS + r0) * NS;
    const ushort* vh = vthi + (size_t)b * VD * NS;
    const ushort* vl = vtlo + (size_t)b * VD * NS;

    float4 ereg[4];
    short8 vregh[5], vregl[5];
    auto loadE = [&](int kt) {
        #pragma unroll
        for (int rep = 0; rep < 4; ++rep) {
            int idx = tid + rep * 256;
            int row = idx >> 5, c4 = idx & 31;
            ereg[rep] = *(const float4*)&arow[(size_t)row * NS + kt + c4 * 4];
        }
    };
    auto loadV = [&](int kt) {
        #pragma unroll
        for (int rep = 0; rep < 5; ++rep) {
            int i = tid + rep * 256;          // VD*16 = 1280 = 5*256 exactly
            int d = i >> 4, c8 = i & 15;
            size_t go = (size_t)d * NS + kt + c8 * 8;
            vregh[rep] = *(const short8*)&vh[go];
            vregl[rep] = *(const short8*)&vl[go];
        }
    };

    f32x4 acc[2][5];
    #pragma unroll
    for (int rf = 0; rf < 2; ++rf)
        #pragma unroll
        for (int ff = 0; ff < 5; ++ff)
            #pragma unroll
            for (int j = 0; j < 4; ++j) acc[rf][ff][j] = 0.0f;

    loadE(0);
    loadV(0);
    __syncthreads();

    for (int kt = 0; kt < NS; kt += 128) {
        // phase 1 (pure stores): normalize ereg -> attn + bf16 split into sA
        #pragma unroll
        for (int rep = 0; rep < 4; ++rep) {
            int idx = tid + rep * 256;
            int row = idx >> 5, c4 = idx & 31;
            float inv = sInvL[row];
            float4 e = ereg[rep];
            e.x *= inv; e.y *= inv; e.z *= inv; e.w *= inv;
            *(float4*)&arow[(size_t)row * NS + kt + c4 * 4] = e;
            ushort h0 = f2bf(e.x), h1 = f2bf(e.y), h2 = f2bf(e.z), h3 = f2bf(e.w);
            ushort l0 = f2bf(e.x - bf2f(h0)), l1 = f2bf(e.y - bf2f(h1));
            ushort l2 = f2bf(e.z - bf2f(h2)), l3 = f2bf(e.w - bf2f(h3));
            int so = row * 136 + c4 * 4;
            *(ushort4*)&sAh[so] = make_ushort4(h0, h1, h2, h3);
            *(ushort4*)&sAl[so] = make_ushort4(l0, l1, l2, l3);
        }
        // ds_write prefetched V^T chunk
        #pragma unroll
        for (int rep = 0; rep < 5; ++rep) {
            int i = tid + rep * 256;
            int d = i >> 4, c8 = i & 15;
            *(short8*)&sVh[d * 136 + c8 * 8] = vregh[rep];
            *(short8*)&sVl[d * 136 + c8 * 8] = vregl[rep];
        }
        __syncthreads();

        // issue next chunk's loads; they drain during the MFMA phase
        if (kt + 128 < NS) { loadE(kt + 128); loadV(kt + 128); }

        const int koff = wk * 32 + (lane >> 4) * 8;
        short8 ah[2], al[2];
        #pragma unroll
        for (int rf = 0; rf < 2; ++rf) {
            int ro = (rf * 16 + (lane & 15)) * 136 + koff;
            ah[rf] = *(const short8*)&sAh[ro];
            al[rf] = *(const short8*)&sAl[ro];
        }
        #pragma unroll
        for (int ff = 0; ff < 5; ++ff) {
            int vo = (ff * 16 + (lane & 15)) * 136 + koff;
            short8 bh = *(const short8*)&sVh[vo];
            short8 bl = *(const short8*)&sVl[vo];
            #pragma unroll
            for (int rf = 0; rf < 2; ++rf) {
                acc[rf][ff] = __builtin_amdgcn_mfma_f32_16x16x32_bf16(ah[rf], bh, acc[rf][ff], 0, 0, 0);
                acc[rf][ff] = __builtin_amdgcn_mfma_f32_16x16x32_bf16(ah[rf], bl, acc[rf][ff], 0, 0, 0);
                acc[rf][ff] = __builtin_amdgcn_mfma_f32_16x16x32_bf16(al[rf], bh, acc[rf][ff], 0, 0, 0);
            }
        }
        __syncthreads();   // protect sA/sV rewrite next chunk
    }

    // write k-slice partials into sRed (aliases dead sV region)
    #pragma unroll
    for (int rf = 0; rf < 2; ++rf)
        #pragma unroll
        for (int ff = 0; ff < 5; ++ff)
            #pragma unroll
            for (int j = 0; j < 4; ++j) {
                int r = rf * 16 + (lane >> 4) * 4 + j;
                int d = ff * 16 + (lane & 15);
                sRed[((size_t)wk * 32 + r) * 80 + d] = acc[rf][ff][j];
            }
    __syncthreads();
    for (int i = tid; i < 32 * 80; i += 256) {
        int r = i / 80, d = i - r * 80;
        float s = sRed[(size_t)r * 80 + d] + sRed[(size_t)(32 + r) * 80 + d]
                + sRed[(size_t)(64 + r) * 80 + d] + sRed[(size_t)(96 + r) * 80 + d];
        if (d < ND) out[((size_t)b * NS + r0 + r) * ND + d] = s;
    }
}

extern "C" void kernel_launch(void* const* d_in, const int* in_sizes, int n_in,
                              void* d_out, int out_size, void* d_ws, size_t ws_size,
                              hipStream_t stream) {
    const float* x      = (const float*)d_in[0];
    const float* values = (const float*)d_in[1];
    const float* temp   = (const float*)d_in[2];

    float* out  = (float*)d_out;
    float* attn = out + OUTSZ;

    ushort* xhi  = (ushort*)d_ws;
    ushort* xlo  = xhi + CONVN;
    ushort* vthi = xlo + CONVN;
    ushort* vtlo = vthi + VTN;
    float*  invb = (float*)(vtlo + VTN);

    k0_convert<<<(int)((CONVN + 255) / 256), 256, 0, stream>>>(x, xhi, xlo);
    k0v_transpose<<<dim3(NS / 32, NB), 256, 0, stream>>>(values, vthi, vtlo);

    k1_scores<<<256, 512, 0, stream>>>(xhi, xlo, temp, attn, invb);
    k2_pv<<<512, 256, 0, stream>>>(attn, vthi, vtlo, invb, out);
}

// Round 12
// 110.962 us; speedup vs baseline: 1.5506x; 1.1068x over previous
//
#include <hip/hip_runtime.h>
#include <math.h>

constexpr int NB = 8, NS = 2048, ND = 65;
constexpr int KP = 104;     // padded K stride for x conv (bf16 elems)
constexpr int VD = 80;      // padded d rows for V^T
constexpr size_t OUTSZ = (size_t)NB * NS * ND;
constexpr size_t CONVN = (size_t)NB * NS * KP;   // x conv elems per array
constexpr size_t VTN   = (size_t)NB * VD * NS;   // V^T elems per array
constexpr size_t EGN   = (size_t)NB * NS * NS;   // E u16 elems

typedef short short8 __attribute__((ext_vector_type(8)));
typedef float f32x4 __attribute__((ext_vector_type(4)));

__device__ __forceinline__ ushort f2bf(float f) {
    uint u = __float_as_uint(f);
    return (ushort)((u + 0x7fffu + ((u >> 16) & 1u)) >> 16);   // RNE
}
__device__ __forceinline__ float bf2f(ushort h) {
    return __uint_as_float((uint)h << 16);
}

// ---------------------------------------------------------------------------
// k0x: x fp32 -> (hi, lo) bf16 split arrays, K padded 65->104 with zeros.
// ---------------------------------------------------------------------------
__global__ __launch_bounds__(256)
void k0_convert(const float* __restrict__ x, ushort* __restrict__ xhi,
                ushort* __restrict__ xlo)
{
    size_t i = (size_t)blockIdx.x * 256 + threadIdx.x;
    if (i >= CONVN) return;
    int d = (int)(i % KP);
    size_t row = i / KP;
    ushort h = 0, l = 0;
    if (d < ND) {
        float v = x[row * ND + d];
        h = f2bf(v);
        l = f2bf(v - bf2f(h));
    }
    xhi[i] = h; xlo[i] = l;
}

// ---------------------------------------------------------------------------
// k0v: V [b,t,d] fp32 -> V^T hi/lo bf16 [b, d(80, zero-pad), t(2048)]
// ---------------------------------------------------------------------------
__global__ __launch_bounds__(256)
void k0v_transpose(const float* __restrict__ v, ushort* __restrict__ vthi,
                   ushort* __restrict__ vtlo)
{
    __shared__ float sT[32][66];
    const int tid = threadIdx.x, b = blockIdx.y, t0 = blockIdx.x * 32;
    const float* vb = v + (size_t)b * NS * ND;
    for (int i = tid; i < 32 * ND; i += 256) {
        int t = i / ND, d = i - t * ND;
        sT[t][d] = vb[(size_t)(t0 + t) * ND + d];
    }
    __syncthreads();
    for (int i = tid; i < VD * 32; i += 256) {
        int d = i >> 5, t = i & 31;
        float val = (d < ND) ? sT[t][d] : 0.0f;
        ushort h = f2bf(val);
        ushort l = f2bf(val - bf2f(h));
        size_t o = ((size_t)b * VD + d) * NS + t0 + t;
        vthi[o] = h; vtlo[o] = l;
    }
}

// ===========================================================================
// Shared k1 body: computes E tile values + rowsums. STORE_U16 selects the
// epilogue store: u16 E to eg (primary) or fp32 E to attn (fallback = r11).
// ===========================================================================
template <bool STORE_U16>
__device__ __forceinline__
void k1_body(const ushort* __restrict__ xhi, const ushort* __restrict__ xlo,
             const float* __restrict__ tptr, float* __restrict__ attn,
             ushort* __restrict__ eg, float* __restrict__ invb)
{
    __shared__ __align__(16) ushort sAh[64 * KP], sAl[64 * KP];
    __shared__ __align__(16) ushort sBh[128 * KP], sBl[128 * KP];
    __shared__ float sSum[4][64];

    const int tid = threadIdx.x;
    // XCD swizzle: dispatch d -> logical f = (d%8)*32 + d/8 (bijective, 256%8==0)
    const int f  = (blockIdx.x & 7) * 32 + (blockIdx.x >> 3);
    const int b  = f >> 5;
    const int r0 = (f & 31) * 64;
    const int lane = tid & 63;
    const int w  = tid >> 6;
    const int wr = w >> 2;          // 0..1  (32-row slab)
    const int wc = w & 3;           // 0..3  (32-col slab)
    const float invT = 1.0f / (tptr[0] + 1e-8f);
    const bool fastT = (invT == 1.0f);

    const ushort* xhb = xhi + (size_t)b * NS * KP;
    const ushort* xlb = xlo + (size_t)b * NS * KP;
    float*  arow = attn + ((size_t)b * NS + r0) * NS;
    ushort* erow = eg   + ((size_t)b * NS + r0) * NS;

    {
        const uint4* sh = (const uint4*)(xhb + (size_t)r0 * KP);
        const uint4* sl = (const uint4*)(xlb + (size_t)r0 * KP);
        uint4* dh = (uint4*)sAh; uint4* dl = (uint4*)sAl;
        for (int i = tid; i < 64 * KP / 8; i += 512) { dh[i] = sh[i]; dl[i] = sl[i]; }
    }
    __syncthreads();
    if (tid < 64) { sAh[tid * KP] ^= 0x8000; sAl[tid * KP] ^= 0x8000; }  // negate time dim

    float rsum[2][4];
    #pragma unroll
    for (int rf = 0; rf < 2; ++rf)
        #pragma unroll
        for (int j = 0; j < 4; ++j) rsum[rf][j] = 0.0f;

    for (int tc = 0; tc < NS; tc += 128) {
        __syncthreads();
        {
            const uint4* gh = (const uint4*)(xhb + (size_t)tc * KP);
            const uint4* gl = (const uint4*)(xlb + (size_t)tc * KP);
            uint4* dh = (uint4*)sBh; uint4* dl = (uint4*)sBl;
            for (int i = tid; i < 128 * KP / 8; i += 512) { dh[i] = gh[i]; dl[i] = gl[i]; }
        }
        __syncthreads();

        f32x4 acc[2][2];
        #pragma unroll
        for (int rf = 0; rf < 2; ++rf)
            #pragma unroll
            for (int cf = 0; cf < 2; ++cf)
                #pragma unroll
                for (int j = 0; j < 4; ++j) acc[rf][cf][j] = 0.0f;

        #pragma unroll
        for (int kc = 0; kc < 3; ++kc) {
            const int koff = kc * 32 + (lane >> 4) * 8;
            short8 ah[2], al[2], bh[2], bl[2];
            #pragma unroll
            for (int rf = 0; rf < 2; ++rf) {
                int ro = (wr * 32 + rf * 16 + (lane & 15)) * KP + koff;
                ah[rf] = *(const short8*)&sAh[ro];
                al[rf] = *(const short8*)&sAl[ro];
            }
            #pragma unroll
            for (int cf = 0; cf < 2; ++cf) {
                int co = (wc * 32 + cf * 16 + (lane & 15)) * KP + koff;
                bh[cf] = *(const short8*)&sBh[co];
                bl[cf] = *(const short8*)&sBl[co];
            }
            #pragma unroll
            for (int rf = 0; rf < 2; ++rf)
                #pragma unroll
                for (int cf = 0; cf < 2; ++cf) {
                    acc[rf][cf] = __builtin_amdgcn_mfma_f32_16x16x32_bf16(ah[rf], bh[cf], acc[rf][cf], 0, 0, 0);
                    acc[rf][cf] = __builtin_amdgcn_mfma_f32_16x16x32_bf16(ah[rf], bl[cf], acc[rf][cf], 0, 0, 0);
                    acc[rf][cf] = __builtin_amdgcn_mfma_f32_16x16x32_bf16(al[rf], bh[cf], acc[rf][cf], 0, 0, 0);
                }
        }

        float ev[2][2][4];
        #pragma unroll
        for (int rf = 0; rf < 2; ++rf)
            #pragma unroll
            for (int cf = 0; cf < 2; ++cf)
                #pragma unroll
                for (int j = 0; j < 4; ++j) {
                    float z = -acc[rf][cf][j];
                    z = fminf(fmaxf(z, 1.0000001f), 50.0f);
                    float w2 = z + __fsqrt_rn(z * z - 1.0f);
                    float e = fastT ? __builtin_amdgcn_rcpf(w2)
                                    : __expf(-__logf(w2) * invT);
                    ev[rf][cf][j] = e;
                    rsum[rf][j] += e;
                }
        #pragma unroll
        for (int rf = 0; rf < 2; ++rf)
            #pragma unroll
            for (int j = 0; j < 4; ++j) {
                int row = wr * 32 + rf * 16 + (lane >> 4) * 4 + j;
                #pragma unroll
                for (int cf = 0; cf < 2; ++cf) {
                    int col = tc + wc * 32 + cf * 16 + (lane & 15);
                    if (STORE_U16)
                        erow[(size_t)row * NS + col] =
                            (ushort)__float2uint_rn(ev[rf][cf][j] * 65535.0f);
                    else
                        arow[(size_t)row * NS + col] = ev[rf][cf][j];
                }
            }
    }

    #pragma unroll
    for (int rf = 0; rf < 2; ++rf)
        #pragma unroll
        for (int j = 0; j < 4; ++j) {
            float v = rsum[rf][j];
            v += __shfl_xor(v, 1, 64);
            v += __shfl_xor(v, 2, 64);
            v += __shfl_xor(v, 4, 64);
            v += __shfl_xor(v, 8, 64);
            if ((lane & 15) == 0)
                sSum[wc][wr * 32 + rf * 16 + (lane >> 4) * 4 + j] = v;
        }
    __syncthreads();
    if (tid < 64)
        invb[(size_t)b * NS + r0 + tid] =
            1.0f / (sSum[0][tid] + sSum[1][tid] + sSum[2][tid] + sSum[3][tid]);
}

__global__ __launch_bounds__(512, 4)
void k1_scores(const ushort* __restrict__ xhi, const ushort* __restrict__ xlo,
               const float* __restrict__ tptr, float* __restrict__ attn,
               float* __restrict__ invb)
{ k1_body<false>(xhi, xlo, tptr, attn, nullptr, invb); }

__global__ __launch_bounds__(512, 4)
void k1u_scores(const ushort* __restrict__ xhi, const ushort* __restrict__ xlo,
                const float* __restrict__ tptr, ushort* __restrict__ eg,
                float* __restrict__ invb)
{ k1_body<true>(xhi, xlo, tptr, nullptr, eg, invb); }

// ---------------------------------------------------------------------------
// k2 fallback (r11-proven): E fp32 in attn buffer, in-place normalize.
// ---------------------------------------------------------------------------
__global__ __launch_bounds__(256, 2)
void k2_pv(float* __restrict__ attn, const ushort* __restrict__ vthi,
           const ushort* __restrict__ vtlo, const float* __restrict__ invb,
           float* __restrict__ out)
{
    __shared__ __align__(16) char smem[(32 * 136 * 2 + 80 * 136 * 2) * 2];
    ushort* sAh = (ushort*)smem;
    ushort* sAl = sAh + 32 * 136;
    ushort* sVh = sAl + 32 * 136;
    ushort* sVl = sVh + 80 * 136;
    float*  sRed = (float*)(sAl + 32 * 136);
    __shared__ float sInvL[32];

    const int tid = threadIdx.x;
    const int f  = (blockIdx.x & 7) * 64 + (blockIdx.x >> 3);
    const int b  = f >> 6;
    const int r0 = (f & 63) * 32;
    const int lane = tid & 63;
    const int wk = tid >> 6;

    if (tid < 32) sInvL[tid] = invb[(size_t)b * NS + r0 + tid];

    float* arow = attn + ((size_t)b * NS + r0) * NS;
    const ushort* vh = vthi + (size_t)b * VD * NS;
    const ushort* vl = vtlo + (size_t)b * VD * NS;

    float4 ereg[4];
    short8 vregh[5], vregl[5];
    auto loadE = [&](int kt) {
        #pragma unroll
        for (int rep = 0; rep < 4; ++rep) {
            int idx = tid + rep * 256;
            int row = idx >> 5, c4 = idx & 31;
            ereg[rep] = *(const float4*)&arow[(size_t)row * NS + kt + c4 * 4];
        }
    };
    auto loadV = [&](int kt) {
        #pragma unroll
        for (int rep = 0; rep < 5; ++rep) {
            int i = tid + rep * 256;
            int d = i >> 4, c8 = i & 15;
            size_t go = (size_t)d * NS + kt + c8 * 8;
            vregh[rep] = *(const short8*)&vh[go];
            vregl[rep] = *(const short8*)&vl[go];
        }
    };

    f32x4 acc[2][5];
    #pragma unroll
    for (int rf = 0; rf < 2; ++rf)
        #pragma unroll
        for (int ff = 0; ff < 5; ++ff)
            #pragma unroll
            for (int j = 0; j < 4; ++j) acc[rf][ff][j] = 0.0f;

    loadE(0);
    loadV(0);
    __syncthreads();

    for (int kt = 0; kt < NS; kt += 128) {
        #pragma unroll
        for (int rep = 0; rep < 4; ++rep) {
            int idx = tid + rep * 256;
            int row = idx >> 5, c4 = idx & 31;
            float inv = sInvL[row];
            float4 e = ereg[rep];
            e.x *= inv; e.y *= inv; e.z *= inv; e.w *= inv;
            *(float4*)&arow[(size_t)row * NS + kt + c4 * 4] = e;
            ushort h0 = f2bf(e.x), h1 = f2bf(e.y), h2 = f2bf(e.z), h3 = f2bf(e.w);
            ushort l0 = f2bf(e.x - bf2f(h0)), l1 = f2bf(e.y - bf2f(h1));
            ushort l2 = f2bf(e.z - bf2f(h2)), l3 = f2bf(e.w - bf2f(h3));
            int so = row * 136 + c4 * 4;
            *(ushort4*)&sAh[so] = make_ushort4(h0, h1, h2, h3);
            *(ushort4*)&sAl[so] = make_ushort4(l0, l1, l2, l3);
        }
        #pragma unroll
        for (int rep = 0; rep < 5; ++rep) {
            int i = tid + rep * 256;
            int d = i >> 4, c8 = i & 15;
            *(short8*)&sVh[d * 136 + c8 * 8] = vregh[rep];
            *(short8*)&sVl[d * 136 + c8 * 8] = vregl[rep];
        }
        __syncthreads();

        if (kt + 128 < NS) { loadE(kt + 128); loadV(kt + 128); }

        const int koff = wk * 32 + (lane >> 4) * 8;
        short8 ah[2], al[2];
        #pragma unroll
        for (int rf = 0; rf < 2; ++rf) {
            int ro = (rf * 16 + (lane & 15)) * 136 + koff;
            ah[rf] = *(const short8*)&sAh[ro];
            al[rf] = *(const short8*)&sAl[ro];
        }
        #pragma unroll
        for (int ff = 0; ff < 5; ++ff) {
            int vo = (ff * 16 + (lane & 15)) * 136 + koff;
            short8 bh = *(const short8*)&sVh[vo];
            short8 bl = *(const short8*)&sVl[vo];
            #pragma unroll
            for (int rf = 0; rf < 2; ++rf) {
                acc[rf][ff] = __builtin_amdgcn_mfma_f32_16x16x32_bf16(ah[rf], bh, acc[rf][ff], 0, 0, 0);
                acc[rf][ff] = __builtin_amdgcn_mfma_f32_16x16x32_bf16(ah[rf], bl, acc[rf][ff], 0, 0, 0);
                acc[rf][ff] = __builtin_amdgcn_mfma_f32_16x16x32_bf16(al[rf], bh, acc[rf][ff], 0, 0, 0);
            }
        }
        __syncthreads();
    }

    #pragma unroll
    for (int rf = 0; rf < 2; ++rf)
        #pragma unroll
        for (int ff = 0; ff < 5; ++ff)
            #pragma unroll
            for (int j = 0; j < 4; ++j) {
                int r = rf * 16 + (lane >> 4) * 4 + j;
                int d = ff * 16 + (lane & 15);
                sRed[((size_t)wk * 32 + r) * 80 + d] = acc[rf][ff][j];
            }
    __syncthreads();
    for (int i = tid; i < 32 * 80; i += 256) {
        int r = i / 80, d = i - r * 80;
        float s = sRed[(size_t)r * 80 + d] + sRed[(size_t)(32 + r) * 80 + d]
                + sRed[(size_t)(64 + r) * 80 + d] + sRed[(size_t)(96 + r) * 80 + d];
        if (d < ND) out[((size_t)b * NS + r0 + r) * ND + d] = s;
    }
}

// ---------------------------------------------------------------------------
// k2u (primary): E u16 in ws (67 MB, L3-hot). Per chunk: T14-prefetched u16
// E regs -> unpack*inv2 -> pure float4 attn store (no RMW) + bf16 split to
// LDS; V^T prefetched likewise; MFMA PV. Same phase skeleton as r11 k2.
// ---------------------------------------------------------------------------
__global__ __launch_bounds__(256, 2)
void k2u_pv(const ushort* __restrict__ eg, const ushort* __restrict__ vthi,
            const ushort* __restrict__ vtlo, const float* __restrict__ invb,
            float* __restrict__ attn, float* __restrict__ out)
{
    __shared__ __align__(16) char smem[(32 * 136 * 2 + 80 * 136 * 2) * 2];
    ushort* sAh = (ushort*)smem;
    ushort* sAl = sAh + 32 * 136;
    ushort* sVh = sAl + 32 * 136;
    ushort* sVl = sVh + 80 * 136;
    float*  sRed = (float*)(sAl + 32 * 136);
    __shared__ float sInvL[32];

    const int tid = threadIdx.x;
    const int f  = (blockIdx.x & 7) * 64 + (blockIdx.x >> 3);
    const int b  = f >> 6;
    const int r0 = (f & 63) * 32;
    const int lane = tid & 63;
    const int wk = tid >> 6;

    if (tid < 32) sInvL[tid] = invb[(size_t)b * NS + r0 + tid] * (1.0f / 65535.0f);

    const ushort* erow = eg + ((size_t)b * NS + r0) * NS;
    float* arow = attn + ((size_t)b * NS + r0) * NS;
    const ushort* vh = vthi + (size_t)b * VD * NS;
    const ushort* vl = vtlo + (size_t)b * VD * NS;

    short8 ereg[2];
    short8 vregh[5], vregl[5];
    auto loadE = [&](int kt) {
        #pragma unroll
        for (int rep = 0; rep < 2; ++rep) {
            int idx = tid + rep * 256;          // 512 = 32 rows x 16 col8-groups
            int row = idx >> 4, c8 = idx & 15;
            ereg[rep] = *(const short8*)&erow[(size_t)row * NS + kt + c8 * 8];
        }
    };
    auto loadV = [&](int kt) {
        #pragma unroll
        for (int rep = 0; rep < 5; ++rep) {
            int i = tid + rep * 256;
            int d = i >> 4, c8 = i & 15;
            size_t go = (size_t)d * NS + kt + c8 * 8;
            vregh[rep] = *(const short8*)&vh[go];
            vregl[rep] = *(const short8*)&vl[go];
        }
    };

    f32x4 acc[2][5];
    #pragma unroll
    for (int rf = 0; rf < 2; ++rf)
        #pragma unroll
        for (int ff = 0; ff < 5; ++ff)
            #pragma unroll
            for (int j = 0; j < 4; ++j) acc[rf][ff][j] = 0.0f;

    loadE(0);
    loadV(0);
    __syncthreads();

    for (int kt = 0; kt < NS; kt += 128) {
        // phase 1: unpack u16 -> en, pure float4 attn store, bf16 split to sA
        #pragma unroll
        for (int rep = 0; rep < 2; ++rep) {
            int idx = tid + rep * 256;
            int row = idx >> 4, c8 = idx & 15;
            float inv2 = sInvL[row];
            float en[8];
            #pragma unroll
            for (int i = 0; i < 8; ++i)
                en[i] = (float)(ushort)ereg[rep][i] * inv2;
            float4 fa = {en[0], en[1], en[2], en[3]};
            float4 fb = {en[4], en[5], en[6], en[7]};
            *(float4*)&arow[(size_t)row * NS + kt + c8 * 8]     = fa;
            *(float4*)&arow[(size_t)row * NS + kt + c8 * 8 + 4] = fb;
            ushort h[8], l[8];
            #pragma unroll
            for (int i = 0; i < 8; ++i) {
                h[i] = f2bf(en[i]);
                l[i] = f2bf(en[i] - bf2f(h[i]));
            }
            int so = row * 136 + c8 * 8;
            *(ushort4*)&sAh[so]     = make_ushort4(h[0], h[1], h[2], h[3]);
            *(ushort4*)&sAh[so + 4] = make_ushort4(h[4], h[5], h[6], h[7]);
            *(ushort4*)&sAl[so]     = make_ushort4(l[0], l[1], l[2], l[3]);
            *(ushort4*)&sAl[so + 4] = make_ushort4(l[4], l[5], l[6], l[7]);
        }
        #pragma unroll
        for (int rep = 0; rep < 5; ++rep) {
            int i = tid + rep * 256;
            int d = i >> 4, c8 = i & 15;
            *(short8*)&sVh[d * 136 + c8 * 8] = vregh[rep];
            *(short8*)&sVl[d * 136 + c8 * 8] = vregl[rep];
        }
        __syncthreads();

        if (kt + 128 < NS) { loadE(kt + 128); loadV(kt + 128); }

        const int koff = wk * 32 + (lane >> 4) * 8;
        short8 ah[2], al[2];
        #pragma unroll
        for (int rf = 0; rf < 2; ++rf) {
            int ro = (rf * 16 + (lane & 15)) * 136 + koff;
            ah[rf] = *(const short8*)&sAh[ro];
            al[rf] = *(const short8*)&sAl[ro];
        }
        #pragma unroll
        for (int ff = 0; ff < 5; ++ff) {
            int vo = (ff * 16 + (lane & 15)) * 136 + koff;
            short8 bh = *(const short8*)&sVh[vo];
            short8 bl = *(const short8*)&sVl[vo];
            #pragma unroll
            for (int rf = 0; rf < 2; ++rf) {
                acc[rf][ff] = __builtin_amdgcn_mfma_f32_16x16x32_bf16(ah[rf], bh, acc[rf][ff], 0, 0, 0);
                acc[rf][ff] = __builtin_amdgcn_mfma_f32_16x16x32_bf16(ah[rf], bl, acc[rf][ff], 0, 0, 0);
                acc[rf][ff] = __builtin_amdgcn_mfma_f32_16x16x32_bf16(al[rf], bh, acc[rf][ff], 0, 0, 0);
            }
        }
        __syncthreads();
    }

    #pragma unroll
    for (int rf = 0; rf < 2; ++rf)
        #pragma unroll
        for (int ff = 0; ff < 5; ++ff)
            #pragma unroll
            for (int j = 0; j < 4; ++j) {
                int r = rf * 16 + (lane >> 4) * 4 + j;
                int d = ff * 16 + (lane & 15);
                sRed[((size_t)wk * 32 + r) * 80 + d] = acc[rf][ff][j];
            }
    __syncthreads();
    for (int i = tid; i < 32 * 80; i += 256) {
        int r = i / 80, d = i - r * 80;
        float s = sRed[(size_t)r * 80 + d] + sRed[(size_t)(32 + r) * 80 + d]
                + sRed[(size_t)(64 + r) * 80 + d] + sRed[(size_t)(96 + r) * 80 + d];
        if (d < ND) out[((size_t)b * NS + r0 + r) * ND + d] = s;
    }
}

extern "C" void kernel_launch(void* const* d_in, const int* in_sizes, int n_in,
                              void* d_out, int out_size, void* d_ws, size_t ws_size,
                              hipStream_t stream) {
    const float* x      = (const float*)d_in[0];
    const float* values = (const float*)d_in[1];
    const float* temp   = (const float*)d_in[2];

    float* out  = (float*)d_out;
    float* attn = out + OUTSZ;

    ushort* xhi  = (ushort*)d_ws;
    ushort* xlo  = xhi + CONVN;
    ushort* vthi = xlo + CONVN;
    ushort* vtlo = vthi + VTN;
    float*  invb = (float*)(vtlo + VTN);
    ushort* eg   = (ushort*)(invb + (size_t)NB * NS);

    const size_t need = (2 * CONVN + 2 * VTN) * sizeof(ushort)
                      + (size_t)NB * NS * sizeof(float) + EGN * sizeof(ushort);
    const bool useU16 = (ws_size >= need);   // ws_size fixed -> deterministic

    k0_convert<<<(int)((CONVN + 255) / 256), 256, 0, stream>>>(x, xhi, xlo);
    k0v_transpose<<<dim3(NS / 32, NB), 256, 0, stream>>>(values, vthi, vtlo);

    if (useU16) {
        k1u_scores<<<256, 512, 0, stream>>>(xhi, xlo, temp, eg, invb);
        k2u_pv<<<512, 256, 0, stream>>>(eg, vthi, vtlo, invb, attn, out);
    } else {
        k1_scores<<<256, 512, 0, stream>>>(xhi, xlo, temp, attn, invb);
        k2_pv<<<512, 256, 0, stream>>>(attn, vthi, vtlo, invb, out);
    }
}

// Round 13
// 104.102 us; speedup vs baseline: 1.6528x; 1.0659x over previous
//
#include <hip/hip_runtime.h>
#include <math.h>

constexpr int NB = 8, NS = 2048, ND = 65;
constexpr int KP = 104;     // padded K stride for x conv (bf16): 2-way-free banks
constexpr int VD = 80;      // padded d rows for V^T
constexpr size_t OUTSZ = (size_t)NB * NS * ND;
constexpr size_t CONVN = (size_t)NB * NS * KP;   // x conv elems per array
constexpr size_t VTN   = (size_t)NB * VD * NS;   // V^T elems (hi only now)
constexpr size_t EGN   = (size_t)NB * NS * NS;   // E u16 elems

typedef short short8 __attribute__((ext_vector_type(8)));
typedef float f32x4 __attribute__((ext_vector_type(4)));

__device__ __forceinline__ ushort f2bf(float f) {
    uint u = __float_as_uint(f);
    return (ushort)((u + 0x7fffu + ((u >> 16) & 1u)) >> 16);   // RNE
}
__device__ __forceinline__ float bf2f(ushort h) {
    return __uint_as_float((uint)h << 16);
}

// ---------------------------------------------------------------------------
// k0x: x fp32 -> (hi, lo) bf16 split, K padded 65->104. Vectorized: one
// thread = one 8-elem group of one row (short8 stores, 16 groups/row).
// ---------------------------------------------------------------------------
__global__ __launch_bounds__(256)
void k0_convert(const float* __restrict__ x, ushort* __restrict__ xhi,
                ushort* __restrict__ xlo)
{
    int i = blockIdx.x * 256 + threadIdx.x;
    int row = i >> 4, sub = i & 15;
    if (row >= NB * NS || sub >= 13) return;   // 13*8 = 104 = KP
    int d0 = sub * 8;
    short8 vh, vl;
    #pragma unroll
    for (int e = 0; e < 8; ++e) {
        int d = d0 + e;
        float v = (d < ND) ? x[(size_t)row * ND + d] : 0.0f;
        ushort h = f2bf(v);
        vh[e] = (short)h;
        vl[e] = (short)f2bf(v - bf2f(h));
    }
    *(short8*)&xhi[(size_t)row * KP + d0] = vh;
    *(short8*)&xlo[(size_t)row * KP + d0] = vl;
}

// ---------------------------------------------------------------------------
// k0v: V [b,t,d] fp32 -> V^T bf16 (hi only) [b, d(80, zero-pad), t(2048)].
// PV error budget: V-bf16 RNE noise -> out std ~1e-4 << threshold.
// ---------------------------------------------------------------------------
__global__ __launch_bounds__(256)
void k0v_transpose(const float* __restrict__ v, ushort* __restrict__ vthi)
{
    __shared__ float sT[32][66];
    const int tid = threadIdx.x, b = blockIdx.y, t0 = blockIdx.x * 32;
    const float* vb = v + (size_t)b * NS * ND;
    for (int i = tid; i < 32 * ND; i += 256) {
        int t = i / ND, d = i - t * ND;
        sT[t][d] = vb[(size_t)(t0 + t) * ND + d];
    }
    __syncthreads();
    for (int i = tid; i < VD * 32; i += 256) {
        int d = i >> 5, t = i & 31;
        float val = (d < ND) ? sT[t][d] : 0.0f;
        vthi[((size_t)b * VD + d) * NS + t0 + t] = f2bf(val);
    }
}

// ---------------------------------------------------------------------------
// k1u: per (batch, 64-row block): S via split-bf16 MFMA (hi*hi+hi*lo+lo*hi),
// E = exp(-acosh(clip)/T) stored u16 fixed-point (E in (0.0099,1]); inv->ws.
// TC=128, 2 blocks/CU, XCD-swizzled grid. fastT: invT==1 => E = rcp(w).
// ---------------------------------------------------------------------------
__global__ __launch_bounds__(512, 4)
void k1u_scores(const ushort* __restrict__ xhi, const ushort* __restrict__ xlo,
                const float* __restrict__ tptr, ushort* __restrict__ eg,
                float* __restrict__ invb)
{
    __shared__ __align__(16) ushort sAh[64 * KP], sAl[64 * KP];
    __shared__ __align__(16) ushort sBh[128 * KP], sBl[128 * KP];
    __shared__ float sSum[4][64];

    const int tid = threadIdx.x;
    // XCD swizzle: dispatch d -> logical f = (d%8)*32 + d/8 (bijective, 256%8==0)
    const int f  = (blockIdx.x & 7) * 32 + (blockIdx.x >> 3);
    const int b  = f >> 5;
    const int r0 = (f & 31) * 64;
    const int lane = tid & 63;
    const int w  = tid >> 6;
    const int wr = w >> 2;          // 0..1  (32-row slab)
    const int wc = w & 3;           // 0..3  (32-col slab)
    const float invT = 1.0f / (tptr[0] + 1e-8f);
    const bool fastT = (invT == 1.0f);

    const ushort* xhb = xhi + (size_t)b * NS * KP;
    const ushort* xlb = xlo + (size_t)b * NS * KP;
    ushort* erow = eg + ((size_t)b * NS + r0) * NS;

    {
        const uint4* sh = (const uint4*)(xhb + (size_t)r0 * KP);
        const uint4* sl = (const uint4*)(xlb + (size_t)r0 * KP);
        uint4* dh = (uint4*)sAh; uint4* dl = (uint4*)sAl;
        for (int i = tid; i < 64 * KP / 8; i += 512) { dh[i] = sh[i]; dl[i] = sl[i]; }
    }
    __syncthreads();
    if (tid < 64) { sAh[tid * KP] ^= 0x8000; sAl[tid * KP] ^= 0x8000; }  // negate time dim

    float rsum[2][4];
    #pragma unroll
    for (int rf = 0; rf < 2; ++rf)
        #pragma unroll
        for (int j = 0; j < 4; ++j) rsum[rf][j] = 0.0f;

    for (int tc = 0; tc < NS; tc += 128) {
        __syncthreads();
        {
            const uint4* gh = (const uint4*)(xhb + (size_t)tc * KP);
            const uint4* gl = (const uint4*)(xlb + (size_t)tc * KP);
            uint4* dh = (uint4*)sBh; uint4* dl = (uint4*)sBl;
            for (int i = tid; i < 128 * KP / 8; i += 512) { dh[i] = gh[i]; dl[i] = gl[i]; }
        }
        __syncthreads();

        f32x4 acc[2][2];
        #pragma unroll
        for (int rf = 0; rf < 2; ++rf)
            #pragma unroll
            for (int cf = 0; cf < 2; ++cf)
                #pragma unroll
                for (int j = 0; j < 4; ++j) acc[rf][cf][j] = 0.0f;

        #pragma unroll
        for (int kc = 0; kc < 3; ++kc) {
            const int koff = kc * 32 + (lane >> 4) * 8;
            short8 ah[2], al[2], bh[2], bl[2];
            #pragma unroll
            for (int rf = 0; rf < 2; ++rf) {
                int ro = (wr * 32 + rf * 16 + (lane & 15)) * KP + koff;
                ah[rf] = *(const short8*)&sAh[ro];
                al[rf] = *(const short8*)&sAl[ro];
            }
            #pragma unroll
            for (int cf = 0; cf < 2; ++cf) {
                int co = (wc * 32 + cf * 16 + (lane & 15)) * KP + koff;
                bh[cf] = *(const short8*)&sBh[co];
                bl[cf] = *(const short8*)&sBl[co];
            }
            #pragma unroll
            for (int rf = 0; rf < 2; ++rf)
                #pragma unroll
                for (int cf = 0; cf < 2; ++cf) {
                    acc[rf][cf] = __builtin_amdgcn_mfma_f32_16x16x32_bf16(ah[rf], bh[cf], acc[rf][cf], 0, 0, 0);
                    acc[rf][cf] = __builtin_amdgcn_mfma_f32_16x16x32_bf16(ah[rf], bl[cf], acc[rf][cf], 0, 0, 0);
                    acc[rf][cf] = __builtin_amdgcn_mfma_f32_16x16x32_bf16(al[rf], bh[cf], acc[rf][cf], 0, 0, 0);
                }
        }

        float ev[2][2][4];
        #pragma unroll
        for (int rf = 0; rf < 2; ++rf)
            #pragma unroll
            for (int cf = 0; cf < 2; ++cf)
                #pragma unroll
                for (int j = 0; j < 4; ++j) {
                    float z = -acc[rf][cf][j];
                    z = fminf(fmaxf(z, 1.0000001f), 50.0f);
                    float w2 = z + __fsqrt_rn(z * z - 1.0f);
                    float e = fastT ? __builtin_amdgcn_rcpf(w2)
                                    : __expf(-__logf(w2) * invT);
                    ev[rf][cf][j] = e;
                    rsum[rf][j] += e;
                }
        #pragma unroll
        for (int rf = 0; rf < 2; ++rf)
            #pragma unroll
            for (int j = 0; j < 4; ++j) {
                int row = wr * 32 + rf * 16 + (lane >> 4) * 4 + j;
                #pragma unroll
                for (int cf = 0; cf < 2; ++cf) {
                    int col = tc + wc * 32 + cf * 16 + (lane & 15);
                    erow[(size_t)row * NS + col] =
                        (ushort)__float2uint_rn(ev[rf][cf][j] * 65535.0f);
                }
            }
    }

    #pragma unroll
    for (int rf = 0; rf < 2; ++rf)
        #pragma unroll
        for (int j = 0; j < 4; ++j) {
            float v = rsum[rf][j];
            v += __shfl_xor(v, 1, 64);
            v += __shfl_xor(v, 2, 64);
            v += __shfl_xor(v, 4, 64);
            v += __shfl_xor(v, 8, 64);
            if ((lane & 15) == 0)
                sSum[wc][wr * 32 + rf * 16 + (lane >> 4) * 4 + j] = v;
        }
    __syncthreads();
    if (tid < 64)
        invb[(size_t)b * NS + r0 + tid] =
            1.0f / (sSum[0][tid] + sSum[1][tid] + sSum[2][tid] + sSum[3][tid]);
}

// ---------------------------------------------------------------------------
// k2u: per (batch, 32-row block): T14-prefetched u16 E + V^T regs; phase 1 =
// unpack*inv -> pure float4 attn store + P bf16 hi/lo split to LDS + V^T
// ds_write; PV = 2-product MFMA (ph*vh + pl*vh; V single bf16 per error
// budget). LDS 41 KB -> 3 blocks/CU. sRed (40960 B) aliases entire staging.
// ---------------------------------------------------------------------------
__global__ __launch_bounds__(256, 3)
void k2u_pv(const ushort* __restrict__ eg, const ushort* __restrict__ vthi,
            const float* __restrict__ invb, float* __restrict__ attn,
            float* __restrict__ out)
{
    __shared__ __align__(16) char smem[40960];
    ushort* sAh = (ushort*)smem;            // 32*136 u16
    ushort* sAl = sAh + 32 * 136;           // 32*136
    ushort* sVh = sAl + 32 * 136;           // 80*136  (end 39168 B)
    float*  sRed = (float*)smem;            // 4*32*80*4 = 40960 B (post-loop)
    __shared__ float sInvL[32];

    const int tid = threadIdx.x;
    // XCD swizzle: dispatch d -> logical f = (d%8)*64 + d/8 (bijective, 512%8==0)
    const int f  = (blockIdx.x & 7) * 64 + (blockIdx.x >> 3);
    const int b  = f >> 6;
    const int r0 = (f & 63) * 32;
    const int lane = tid & 63;
    const int wk = tid >> 6;          // k-slice 0..3 within each 128-chunk

    if (tid < 32) sInvL[tid] = invb[(size_t)b * NS + r0 + tid] * (1.0f / 65535.0f);

    const ushort* erow = eg + ((size_t)b * NS + r0) * NS;
    float* arow = attn + ((size_t)b * NS + r0) * NS;
    const ushort* vh = vthi + (size_t)b * VD * NS;

    short8 ereg[2];
    short8 vregh[5];
    auto loadE = [&](int kt) {
        #pragma unroll
        for (int rep = 0; rep < 2; ++rep) {
            int idx = tid + rep * 256;          // 512 = 32 rows x 16 col8-groups
            int row = idx >> 4, c8 = idx & 15;
            ereg[rep] = *(const short8*)&erow[(size_t)row * NS + kt + c8 * 8];
        }
    };
    auto loadV = [&](int kt) {
        #pragma unroll
        for (int rep = 0; rep < 5; ++rep) {
            int i = tid + rep * 256;
            int d = i >> 4, c8 = i & 15;
            vregh[rep] = *(const short8*)&vh[(size_t)d * NS + kt + c8 * 8];
        }
    };

    f32x4 acc[2][5];
    #pragma unroll
    for (int rf = 0; rf < 2; ++rf)
        #pragma unroll
        for (int ff = 0; ff < 5; ++ff)
            #pragma unroll
            for (int j = 0; j < 4; ++j) acc[rf][ff][j] = 0.0f;

    loadE(0);
    loadV(0);
    __syncthreads();

    for (int kt = 0; kt < NS; kt += 128) {
        // phase 1: unpack u16 -> en, pure float4 attn store, bf16 split to sA
        #pragma unroll
        for (int rep = 0; rep < 2; ++rep) {
            int idx = tid + rep * 256;
            int row = idx >> 4, c8 = idx & 15;
            float inv2 = sInvL[row];
            float en[8];
            #pragma unroll
            for (int i = 0; i < 8; ++i)
                en[i] = (float)(ushort)ereg[rep][i] * inv2;
            float4 fa = {en[0], en[1], en[2], en[3]};
            float4 fb = {en[4], en[5], en[6], en[7]};
            *(float4*)&arow[(size_t)row * NS + kt + c8 * 8]     = fa;
            *(float4*)&arow[(size_t)row * NS + kt + c8 * 8 + 4] = fb;
            ushort h[8], l[8];
            #pragma unroll
            for (int i = 0; i < 8; ++i) {
                h[i] = f2bf(en[i]);
                l[i] = f2bf(en[i] - bf2f(h[i]));
            }
            int so = row * 136 + c8 * 8;
            *(ushort4*)&sAh[so]     = make_ushort4(h[0], h[1], h[2], h[3]);
            *(ushort4*)&sAh[so + 4] = make_ushort4(h[4], h[5], h[6], h[7]);
            *(ushort4*)&sAl[so]     = make_ushort4(l[0], l[1], l[2], l[3]);
            *(ushort4*)&sAl[so + 4] = make_ushort4(l[4], l[5], l[6], l[7]);
        }
        #pragma unroll
        for (int rep = 0; rep < 5; ++rep) {
            int i = tid + rep * 256;
            int d = i >> 4, c8 = i & 15;
            *(short8*)&sVh[d * 136 + c8 * 8] = vregh[rep];
        }
        __syncthreads();

        if (kt + 128 < NS) { loadE(kt + 128); loadV(kt + 128); }

        const int koff = wk * 32 + (lane >> 4) * 8;
        short8 ah[2], al[2];
        #pragma unroll
        for (int rf = 0; rf < 2; ++rf) {
            int ro = (rf * 16 + (lane & 15)) * 136 + koff;
            ah[rf] = *(const short8*)&sAh[ro];
            al[rf] = *(const short8*)&sAl[ro];
        }
        #pragma unroll
        for (int ff = 0; ff < 5; ++ff) {
            short8 bh = *(const short8*)&sVh[(ff * 16 + (lane & 15)) * 136 + koff];
            #pragma unroll
            for (int rf = 0; rf < 2; ++rf) {
                acc[rf][ff] = __builtin_amdgcn_mfma_f32_16x16x32_bf16(ah[rf], bh, acc[rf][ff], 0, 0, 0);
                acc[rf][ff] = __builtin_amdgcn_mfma_f32_16x16x32_bf16(al[rf], bh, acc[rf][ff], 0, 0, 0);
            }
        }
        __syncthreads();
    }

    // k-slice partials -> sRed (aliases dead staging), reduce, write out
    #pragma unroll
    for (int rf = 0; rf < 2; ++rf)
        #pragma unroll
        for (int ff = 0; ff < 5; ++ff)
            #pragma unroll
            for (int j = 0; j < 4; ++j) {
                int r = rf * 16 + (lane >> 4) * 4 + j;
                int d = ff * 16 + (lane & 15);
                sRed[((size_t)wk * 32 + r) * 80 + d] = acc[rf][ff][j];
            }
    __syncthreads();
    for (int i = tid; i < 32 * 80; i += 256) {
        int r = i / 80, d = i - r * 80;
        float s = sRed[(size_t)r * 80 + d] + sRed[(size_t)(32 + r) * 80 + d]
                + sRed[(size_t)(64 + r) * 80 + d] + sRed[(size_t)(96 + r) * 80 + d];
        if (d < ND) out[((size_t)b * NS + r0 + r) * ND + d] = s;
    }
}

extern "C" void kernel_launch(void* const* d_in, const int* in_sizes, int n_in,
                              void* d_out, int out_size, void* d_ws, size_t ws_size,
                              hipStream_t stream) {
    const float* x      = (const float*)d_in[0];
    const float* values = (const float*)d_in[1];
    const float* temp   = (const float*)d_in[2];

    float* out  = (float*)d_out;
    float* attn = out + OUTSZ;

    // ws: xhi/xlo 6.97MB + vthi 2.62MB + invb 64KB + eg 67.1MB ~ 77MB
    // (r12 proved ws_size >= 79.6MB: the u16 path ran and matched prediction)
    ushort* xhi  = (ushort*)d_ws;
    ushort* xlo  = xhi + CONVN;
    ushort* vthi = xlo + CONVN;
    float*  invb = (float*)(vthi + VTN);
    ushort* eg   = (ushort*)(invb + (size_t)NB * NS);

    k0_convert<<<(NB * NS * 16) / 256, 256, 0, stream>>>(x, xhi, xlo);
    k0v_transpose<<<dim3(NS / 32, NB), 256, 0, stream>>>(values, vthi);

    k1u_scores<<<256, 512, 0, stream>>>(xhi, xlo, temp, eg, invb);
    k2u_pv<<<512, 256, 0, stream>>>(eg, vthi, invb, attn, out);
}

// Round 14
// 94.516 us; speedup vs baseline: 1.8204x; 1.1014x over previous
//
#include <hip/hip_runtime.h>
#include <math.h>

constexpr int NB = 8, NS = 2048, ND = 65;
constexpr int KX = 64;      // packed x stride (d 0..63); d=64 kept separate in fp32
constexpr int LP = 68;      // LDS row stride for QK tiles: 136B rows -> 2-way-free banks
constexpr int VD = 80;      // padded d rows for V^T
constexpr size_t OUTSZ = (size_t)NB * NS * ND;
constexpr size_t CONVN = (size_t)NB * NS * KX;   // packed x elems per array
constexpr size_t VTN   = (size_t)NB * VD * NS;   // V^T elems (hi only)

typedef short short8 __attribute__((ext_vector_type(8)));
typedef float f32x4 __attribute__((ext_vector_type(4)));

union S8U { short8 v; ushort4 h[2]; };
__device__ __forceinline__ short8 ld8(const ushort* p) {   // 8B-aligned LDS read
    S8U u; u.h[0] = *(const ushort4*)p; u.h[1] = *(const ushort4*)(p + 4); return u.v;
}

__device__ __forceinline__ ushort f2bf(float f) {
    uint u = __float_as_uint(f);
    return (ushort)((u + 0x7fffu + ((u >> 16) & 1u)) >> 16);   // RNE
}
__device__ __forceinline__ float bf2f(ushort h) {
    return __uint_as_float((uint)h << 16);
}

// ---------------------------------------------------------------------------
// k0x: x fp32 -> (hi, lo) bf16 packed KX=64 (d 0..63) + x64 fp32 (d=64).
// Thread = one 8-elem group of one row; short8 16B-aligned stores.
// ---------------------------------------------------------------------------
__global__ __launch_bounds__(256)
void k0_convert(const float* __restrict__ x, ushort* __restrict__ xhi,
                ushort* __restrict__ xlo, float* __restrict__ x64)
{
    int i = blockIdx.x * 256 + threadIdx.x;
    int row = i >> 3, g = i & 7;
    if (row >= NB * NS) return;
    int d0 = g * 8;
    short8 vh, vl;
    #pragma unroll
    for (int e = 0; e < 8; ++e) {
        float v = x[(size_t)row * ND + d0 + e];
        ushort h = f2bf(v);
        vh[e] = (short)h;
        vl[e] = (short)f2bf(v - bf2f(h));
    }
    *(short8*)&xhi[(size_t)row * KX + d0] = vh;
    *(short8*)&xlo[(size_t)row * KX + d0] = vl;
    if (g == 0) x64[row] = x[(size_t)row * ND + 64];
}

// ---------------------------------------------------------------------------
// k0v: V [b,t,d] fp32 -> V^T bf16 (hi only) [b, d(80, zero-pad), t(2048)].
// ---------------------------------------------------------------------------
__global__ __launch_bounds__(256)
void k0v_transpose(const float* __restrict__ v, ushort* __restrict__ vthi)
{
    __shared__ float sT[32][66];
    const int tid = threadIdx.x, b = blockIdx.y, t0 = blockIdx.x * 32;
    const float* vb = v + (size_t)b * NS * ND;
    for (int i = tid; i < 32 * ND; i += 256) {
        int t = i / ND, d = i - t * ND;
        sT[t][d] = vb[(size_t)(t0 + t) * ND + d];
    }
    __syncthreads();
    for (int i = tid; i < VD * 32; i += 256) {
        int d = i >> 5, t = i & 31;
        float val = (d < ND) ? sT[t][d] : 0.0f;
        vthi[((size_t)b * VD + d) * NS + t0 + t] = f2bf(val);
    }
}

// ---------------------------------------------------------------------------
// k1u: per (batch, 64-row block): S(d 0..63) via split-bf16 MFMA, 2 K-chunks
// only; d=64 term added in epilogue as fp32 FMA (exact). E = z - sqrt(z^2-1)
// (== 1/(z+sqrt(z^2-1)), rcp-free) stored u16; inv[row] -> ws.
// LDS 51.5 KB, stride-68 tiles (2-way-free banks, 8B frag reads).
// ---------------------------------------------------------------------------
__global__ __launch_bounds__(512, 4)
void k1u_scores(const ushort* __restrict__ xhi, const ushort* __restrict__ xlo,
                const float* __restrict__ x64, const float* __restrict__ tptr,
                ushort* __restrict__ eg, float* __restrict__ invb)
{
    __shared__ __align__(16) ushort sAh[64 * LP], sAl[64 * LP];   // 8704 B each
    __shared__ __align__(16) ushort sBh[128 * LP], sBl[128 * LP]; // 17408 B each
    __shared__ float sB64[128];

    const int tid = threadIdx.x;
    // XCD swizzle: dispatch d -> logical f = (d%8)*32 + d/8 (bijective, 256%8==0)
    const int f  = (blockIdx.x & 7) * 32 + (blockIdx.x >> 3);
    const int b  = f >> 5;
    const int r0 = (f & 31) * 64;
    const int lane = tid & 63;
    const int q = lane >> 4, c = lane & 15;
    const int w  = tid >> 6;
    const int wr = w >> 2;          // 0..1  (32-row slab)
    const int wc = w & 3;           // 0..3  (32-col slab)
    const float invT = 1.0f / (tptr[0] + 1e-8f);
    const bool fastT = (invT == 1.0f);

    const ushort* xhb = xhi + (size_t)b * NS * KX;
    const ushort* xlb = xlo + (size_t)b * NS * KX;
    const float*  x64b = x64 + (size_t)b * NS;
    ushort* erow = eg + ((size_t)b * NS + r0) * NS;

    // stage A rows once (64 x 64, hi+lo) into stride-68 tiles
    for (int i = tid; i < 64 * 8; i += 512) {
        int row = i >> 3, g = i & 7;
        uint4 vh = *(const uint4*)&xhb[(size_t)(r0 + row) * KX + g * 8];
        uint4 vl = *(const uint4*)&xlb[(size_t)(r0 + row) * KX + g * 8];
        int so = row * LP + g * 8;
        *(uint2*)&sAh[so]     = make_uint2(vh.x, vh.y);
        *(uint2*)&sAh[so + 4] = make_uint2(vh.z, vh.w);
        *(uint2*)&sAl[so]     = make_uint2(vl.x, vl.y);
        *(uint2*)&sAl[so + 4] = make_uint2(vl.z, vl.w);
    }
    __syncthreads();
    if (tid < 64) { sAh[tid * LP] ^= 0x8000; sAl[tid * LP] ^= 0x8000; }  // negate time dim

    // per-lane fp32 d64 A values (the 8 output rows this lane owns)
    float a64r[2][4];
    #pragma unroll
    for (int rf = 0; rf < 2; ++rf)
        #pragma unroll
        for (int j = 0; j < 4; ++j)
            a64r[rf][j] = x64b[r0 + wr * 32 + rf * 16 + q * 4 + j];

    float rsum[2][4];
    #pragma unroll
    for (int rf = 0; rf < 2; ++rf)
        #pragma unroll
        for (int j = 0; j < 4; ++j) rsum[rf][j] = 0.0f;

    for (int tc = 0; tc < NS; tc += 128) {
        __syncthreads();
        for (int i = tid; i < 128 * 8; i += 512) {
            int row = i >> 3, g = i & 7;
            uint4 vh = *(const uint4*)&xhb[(size_t)(tc + row) * KX + g * 8];
            uint4 vl = *(const uint4*)&xlb[(size_t)(tc + row) * KX + g * 8];
            int so = row * LP + g * 8;
            *(uint2*)&sBh[so]     = make_uint2(vh.x, vh.y);
            *(uint2*)&sBh[so + 4] = make_uint2(vh.z, vh.w);
            *(uint2*)&sBl[so]     = make_uint2(vl.x, vl.y);
            *(uint2*)&sBl[so + 4] = make_uint2(vl.z, vl.w);
        }
        if (tid < 128) sB64[tid] = x64b[tc + tid];
        __syncthreads();

        f32x4 acc[2][2];
        #pragma unroll
        for (int rf = 0; rf < 2; ++rf)
            #pragma unroll
            for (int cf = 0; cf < 2; ++cf)
                #pragma unroll
                for (int j = 0; j < 4; ++j) acc[rf][cf][j] = 0.0f;

        #pragma unroll
        for (int kc = 0; kc < 2; ++kc) {
            const int koff = kc * 32 + q * 8;
            short8 ah[2], al[2], bh[2], bl[2];
            #pragma unroll
            for (int rf = 0; rf < 2; ++rf) {
                int ro = (wr * 32 + rf * 16 + c) * LP + koff;
                ah[rf] = ld8(&sAh[ro]);
                al[rf] = ld8(&sAl[ro]);
            }
            #pragma unroll
            for (int cf = 0; cf < 2; ++cf) {
                int co = (wc * 32 + cf * 16 + c) * LP + koff;
                bh[cf] = ld8(&sBh[co]);
                bl[cf] = ld8(&sBl[co]);
            }
            #pragma unroll
            for (int rf = 0; rf < 2; ++rf)
                #pragma unroll
                for (int cf = 0; cf < 2; ++cf) {
                    acc[rf][cf] = __builtin_amdgcn_mfma_f32_16x16x32_bf16(ah[rf], bh[cf], acc[rf][cf], 0, 0, 0);
                    acc[rf][cf] = __builtin_amdgcn_mfma_f32_16x16x32_bf16(ah[rf], bl[cf], acc[rf][cf], 0, 0, 0);
                    acc[rf][cf] = __builtin_amdgcn_mfma_f32_16x16x32_bf16(al[rf], bh[cf], acc[rf][cf], 0, 0, 0);
                }
        }

        // epilogue: + fp32 d64 term, acosh->exp (rcp-free), u16 store, rowsum
        float b64v[2] = { sB64[wc * 32 + c], sB64[wc * 32 + 16 + c] };
        float ev[2][2][4];
        #pragma unroll
        for (int rf = 0; rf < 2; ++rf)
            #pragma unroll
            for (int cf = 0; cf < 2; ++cf)
                #pragma unroll
                for (int j = 0; j < 4; ++j) {
                    float accf = acc[rf][cf][j] + a64r[rf][j] * b64v[cf];
                    float z = -accf;
                    z = fminf(fmaxf(z, 1.0000001f), 50.0f);
                    float s = __fsqrt_rn(z * z - 1.0f);
                    float e = fastT ? (z - s)                   // == 1/(z+s)
                                    : __expf(-__logf(z + s) * invT);
                    ev[rf][cf][j] = e;
                    rsum[rf][j] += e;
                }
        #pragma unroll
        for (int rf = 0; rf < 2; ++rf)
            #pragma unroll
            for (int j = 0; j < 4; ++j) {
                int row = wr * 32 + rf * 16 + q * 4 + j;
                #pragma unroll
                for (int cf = 0; cf < 2; ++cf) {
                    int col = tc + wc * 32 + cf * 16 + c;
                    erow[(size_t)row * NS + col] =
                        (ushort)__float2uint_rn(ev[rf][cf][j] * 65535.0f);
                }
            }
    }

    __syncthreads();                    // all frag reads done -> sBh reusable
    float* sSum = (float*)sBh;          // [4][64] aliases dead B tile
    #pragma unroll
    for (int rf = 0; rf < 2; ++rf)
        #pragma unroll
        for (int j = 0; j < 4; ++j) {
            float v = rsum[rf][j];
            v += __shfl_xor(v, 1, 64);
            v += __shfl_xor(v, 2, 64);
            v += __shfl_xor(v, 4, 64);
            v += __shfl_xor(v, 8, 64);
            if (c == 0) sSum[wc * 64 + wr * 32 + rf * 16 + q * 4 + j] = v;
        }
    __syncthreads();
    if (tid < 64)
        invb[(size_t)b * NS + r0 + tid] =
            1.0f / (sSum[tid] + sSum[64 + tid] + sSum[128 + tid] + sSum[192 + tid]);
}

// ---------------------------------------------------------------------------
// k2u: per (batch, 32-row block): T14-prefetched u16 E + V^T regs; phase 1 =
// unpack*inv -> pure float4 attn store + P bf16 hi/lo split to LDS + V^T
// ds_write; PV = 2-product MFMA. LDS exactly 40960 B (sInvL folded at 39168,
// sRed aliases all post-loop) -> 4 blocks/CU.
// ---------------------------------------------------------------------------
__global__ __launch_bounds__(256, 4)
void k2u_pv(const ushort* __restrict__ eg, const ushort* __restrict__ vthi,
            const float* __restrict__ invb, float* __restrict__ attn,
            float* __restrict__ out)
{
    __shared__ __align__(16) char smem[40960];
    ushort* sAh = (ushort*)smem;                  // 32*136 u16 [0, 8704)
    ushort* sAl = sAh + 32 * 136;                 // [8704, 17408)
    ushort* sVh = sAl + 32 * 136;                 // 80*136 [17408, 39168)
    float*  sInvL = (float*)(smem + 39168);       // 128 B [39168, 39296)
    float*  sRed = (float*)smem;                  // 40960 B, post-loop only

    const int tid = threadIdx.x;
    // XCD swizzle: dispatch d -> logical f = (d%8)*64 + d/8 (bijective, 512%8==0)
    const int f  = (blockIdx.x & 7) * 64 + (blockIdx.x >> 3);
    const int b  = f >> 6;
    const int r0 = (f & 63) * 32;
    const int lane = tid & 63;
    const int wk = tid >> 6;          // k-slice 0..3 within each 128-chunk

    if (tid < 32) sInvL[tid] = invb[(size_t)b * NS + r0 + tid] * (1.0f / 65535.0f);

    const ushort* erow = eg + ((size_t)b * NS + r0) * NS;
    float* arow = attn + ((size_t)b * NS + r0) * NS;
    const ushort* vh = vthi + (size_t)b * VD * NS;

    short8 ereg[2];
    short8 vregh[5];
    auto loadE = [&](int kt) {
        #pragma unroll
        for (int rep = 0; rep < 2; ++rep) {
            int idx = tid + rep * 256;          // 512 = 32 rows x 16 col8-groups
            int row = idx >> 4, c8 = idx & 15;
            ereg[rep] = *(const short8*)&erow[(size_t)row * NS + kt + c8 * 8];
        }
    };
    auto loadV = [&](int kt) {
        #pragma unroll
        for (int rep = 0; rep < 5; ++rep) {
            int i = tid + rep * 256;
            int d = i >> 4, c8 = i & 15;
            vregh[rep] = *(const short8*)&vh[(size_t)d * NS + kt + c8 * 8];
        }
    };

    f32x4 acc[2][5];
    #pragma unroll
    for (int rf = 0; rf < 2; ++rf)
        #pragma unroll
        for (int ff = 0; ff < 5; ++ff)
            #pragma unroll
            for (int j = 0; j < 4; ++j) acc[rf][ff][j] = 0.0f;

    loadE(0);
    loadV(0);
    __syncthreads();

    for (int kt = 0; kt < NS; kt += 128) {
        // phase 1: unpack u16 -> en, pure float4 attn store, bf16 split to sA
        #pragma unroll
        for (int rep = 0; rep < 2; ++rep) {
            int idx = tid + rep * 256;
            int row = idx >> 4, c8 = idx & 15;
            float inv2 = sInvL[row];
            float en[8];
            #pragma unroll
            for (int i = 0; i < 8; ++i)
                en[i] = (float)(ushort)ereg[rep][i] * inv2;
            float4 fa = {en[0], en[1], en[2], en[3]};
            float4 fb = {en[4], en[5], en[6], en[7]};
            *(float4*)&arow[(size_t)row * NS + kt + c8 * 8]     = fa;
            *(float4*)&arow[(size_t)row * NS + kt + c8 * 8 + 4] = fb;
            ushort h[8], l[8];
            #pragma unroll
            for (int i = 0; i < 8; ++i) {
                h[i] = f2bf(en[i]);
                l[i] = f2bf(en[i] - bf2f(h[i]));
            }
            int so = row * 136 + c8 * 8;
            *(ushort4*)&sAh[so]     = make_ushort4(h[0], h[1], h[2], h[3]);
            *(ushort4*)&sAh[so + 4] = make_ushort4(h[4], h[5], h[6], h[7]);
            *(ushort4*)&sAl[so]     = make_ushort4(l[0], l[1], l[2], l[3]);
            *(ushort4*)&sAl[so + 4] = make_ushort4(l[4], l[5], l[6], l[7]);
        }
        #pragma unroll
        for (int rep = 0; rep < 5; ++rep) {
            int i = tid + rep * 256;
            int d = i >> 4, c8 = i & 15;
            *(short8*)&sVh[d * 136 + c8 * 8] = vregh[rep];
        }
        __syncthreads();

        if (kt + 128 < NS) { loadE(kt + 128); loadV(kt + 128); }

        const int koff = wk * 32 + (lane >> 4) * 8;
        short8 ah[2], al[2];
        #pragma unroll
        for (int rf = 0; rf < 2; ++rf) {
            int ro = (rf * 16 + (lane & 15)) * 136 + koff;
            ah[rf] = *(const short8*)&sAh[ro];
            al[rf] = *(const short8*)&sAl[ro];
        }
        #pragma unroll
        for (int ff = 0; ff < 5; ++ff) {
            short8 bh = *(const short8*)&sVh[(ff * 16 + (lane & 15)) * 136 + koff];
            #pragma unroll
            for (int rf = 0; rf < 2; ++rf) {
                acc[rf][ff] = __builtin_amdgcn_mfma_f32_16x16x32_bf16(ah[rf], bh, acc[rf][ff], 0, 0, 0);
                acc[rf][ff] = __builtin_amdgcn_mfma_f32_16x16x32_bf16(al[rf], bh, acc[rf][ff], 0, 0, 0);
            }
        }
        __syncthreads();
    }

    // k-slice partials -> sRed (aliases all staging), reduce, write out
    #pragma unroll
    for (int rf = 0; rf < 2; ++rf)
        #pragma unroll
        for (int ff = 0; ff < 5; ++ff)
            #pragma unroll
            for (int j = 0; j < 4; ++j) {
                int r = rf * 16 + (lane >> 4) * 4 + j;
                int d = ff * 16 + (lane & 15);
                sRed[((size_t)wk * 32 + r) * 80 + d] = acc[rf][ff][j];
            }
    __syncthreads();
    for (int i = tid; i < 32 * 80; i += 256) {
        int r = i / 80, d = i - r * 80;
        float s = sRed[(size_t)r * 80 + d] + sRed[(size_t)(32 + r) * 80 + d]
                + sRed[(size_t)(64 + r) * 80 + d] + sRed[(size_t)(96 + r) * 80 + d];
        if (d < ND) out[((size_t)b * NS + r0 + r) * ND + d] = s;
    }
}

extern "C" void kernel_launch(void* const* d_in, const int* in_sizes, int n_in,
                              void* d_out, int out_size, void* d_ws, size_t ws_size,
                              hipStream_t stream) {
    const float* x      = (const float*)d_in[0];
    const float* values = (const float*)d_in[1];
    const float* temp   = (const float*)d_in[2];

    float* out  = (float*)d_out;
    float* attn = out + OUTSZ;

    // ws: xhi/xlo 4.19MB x2 + vthi 2.62MB + x64 64KB + invb 64KB + eg 67.1MB
    // ~ 78.3MB (r12/r13 proved ws_size >= 79.2MB: u16 path ran)
    ushort* xhi  = (ushort*)d_ws;
    ushort* xlo  = xhi + CONVN;
    ushort* vthi = xlo + CONVN;
    float*  x64  = (float*)(vthi + VTN);
    float*  invb = x64 + (size_t)NB * NS;
    ushort* eg   = (ushort*)(invb + (size_t)NB * NS);

    k0_convert<<<(NB * NS * 8) / 256, 256, 0, stream>>>(x, xhi, xlo, x64);
    k0v_transpose<<<dim3(NS / 32, NB), 256, 0, stream>>>(values, vthi);

    k1u_scores<<<256, 512, 0, stream>>>(xhi, xlo, x64, temp, eg, invb);
    k2u_pv<<<512, 256, 0, stream>>>(eg, vthi, invb, attn, out);
}

// Round 15
// 93.598 us; speedup vs baseline: 1.8383x; 1.0098x over previous
//
#include <hip/hip_runtime.h>
#include <math.h>

constexpr int NB = 8, NS = 2048, ND = 65;
constexpr int KX = 64;      // packed x stride (d 0..63); d=64 separate fp32
constexpr int LP = 68;      // LDS row stride for QK tiles: 136B rows -> 2-way-free banks
constexpr int VD = 80;      // padded d rows for V^T
constexpr size_t OUTSZ = (size_t)NB * NS * ND;
constexpr size_t CONVN = (size_t)NB * NS * KX;   // packed x elems per array
constexpr size_t VTN   = (size_t)NB * VD * NS;   // V^T elems (hi only)

typedef short short8 __attribute__((ext_vector_type(8)));
typedef float f32x4 __attribute__((ext_vector_type(4)));

union S8U { short8 v; ushort4 h[2]; };
__device__ __forceinline__ short8 ld8(const ushort* p) {   // 8B-aligned LDS read
    S8U u; u.h[0] = *(const ushort4*)p; u.h[1] = *(const ushort4*)(p + 4); return u.v;
}

__device__ __forceinline__ ushort f2bf(float f) {
    uint u = __float_as_uint(f);
    return (ushort)((u + 0x7fffu + ((u >> 16) & 1u)) >> 16);   // RNE
}
__device__ __forceinline__ float bf2f(ushort h) {
    return __uint_as_float((uint)h << 16);
}

// ---------------------------------------------------------------------------
// k0x: x fp32 -> (hi, lo) bf16 packed KX=64 (d 0..63) + x64 fp32 (d=64).
// ---------------------------------------------------------------------------
__global__ __launch_bounds__(256)
void k0_convert(const float* __restrict__ x, ushort* __restrict__ xhi,
                ushort* __restrict__ xlo, float* __restrict__ x64)
{
    int i = blockIdx.x * 256 + threadIdx.x;
    int row = i >> 3, g = i & 7;
    if (row >= NB * NS) return;
    int d0 = g * 8;
    short8 vh, vl;
    #pragma unroll
    for (int e = 0; e < 8; ++e) {
        float v = x[(size_t)row * ND + d0 + e];
        ushort h = f2bf(v);
        vh[e] = (short)h;
        vl[e] = (short)f2bf(v - bf2f(h));
    }
    *(short8*)&xhi[(size_t)row * KX + d0] = vh;
    *(short8*)&xlo[(size_t)row * KX + d0] = vl;
    if (g == 0) x64[row] = x[(size_t)row * ND + 64];
}

// ---------------------------------------------------------------------------
// k0v: V [b,t,d] fp32 -> V^T bf16 (hi only) [b, d(80, zero-pad), t(2048)].
// ---------------------------------------------------------------------------
__global__ __launch_bounds__(256)
void k0v_transpose(const float* __restrict__ v, ushort* __restrict__ vthi)
{
    __shared__ float sT[32][66];
    const int tid = threadIdx.x, b = blockIdx.y, t0 = blockIdx.x * 32;
    const float* vb = v + (size_t)b * NS * ND;
    for (int i = tid; i < 32 * ND; i += 256) {
        int t = i / ND, d = i - t * ND;
        sT[t][d] = vb[(size_t)(t0 + t) * ND + d];
    }
    __syncthreads();
    for (int i = tid; i < VD * 32; i += 256) {
        int d = i >> 5, t = i & 31;
        float val = (d < ND) ? sT[t][d] : 0.0f;
        vthi[((size_t)b * VD + d) * NS + t0 + t] = f2bf(val);
    }
}

// ---------------------------------------------------------------------------
// k1u: per (batch, 64-row block). OPERAND-SWAPPED MFMA: acc = mfma(b, a)
// computes the transposed tile, so lane&15 = S-row and the 4 accumulator
// regs = 4 CONSECUTIVE S-cols -> u16 E stores become ushort4 (8B) writes
// (full 512B/wave lines) instead of 16 scalar 2B stores. d=64 term is a
// fp32 FMA in the epilogue (exact); E = z - sqrt(z^2-1) (rcp-free) u16.
// ---------------------------------------------------------------------------
__global__ __launch_bounds__(512, 4)
void k1u_scores(const ushort* __restrict__ xhi, const ushort* __restrict__ xlo,
                const float* __restrict__ x64, const float* __restrict__ tptr,
                ushort* __restrict__ eg, float* __restrict__ invb)
{
    __shared__ __align__(16) ushort sAh[64 * LP], sAl[64 * LP];   // 8704 B each
    __shared__ __align__(16) ushort sBh[128 * LP], sBl[128 * LP]; // 17408 B each
    __shared__ __align__(16) float sB64[128];

    const int tid = threadIdx.x;
    // XCD swizzle: dispatch d -> logical f = (d%8)*32 + d/8 (bijective, 256%8==0)
    const int f  = (blockIdx.x & 7) * 32 + (blockIdx.x >> 3);
    const int b  = f >> 5;
    const int r0 = (f & 31) * 64;
    const int lane = tid & 63;
    const int q = lane >> 4, c = lane & 15;
    const int w  = tid >> 6;
    const int wr = w >> 2;          // 0..1  (32-row slab)
    const int wc = w & 3;           // 0..3  (32-col slab)
    const float invT = 1.0f / (tptr[0] + 1e-8f);
    const bool fastT = (invT == 1.0f);

    const ushort* xhb = xhi + (size_t)b * NS * KX;
    const ushort* xlb = xlo + (size_t)b * NS * KX;
    const float*  x64b = x64 + (size_t)b * NS;
    ushort* erow = eg + ((size_t)b * NS + r0) * NS;

    // stage A rows once (64 x 64, hi+lo) into stride-68 tiles
    for (int i = tid; i < 64 * 8; i += 512) {
        int row = i >> 3, g = i & 7;
        uint4 vh = *(const uint4*)&xhb[(size_t)(r0 + row) * KX + g * 8];
        uint4 vl = *(const uint4*)&xlb[(size_t)(r0 + row) * KX + g * 8];
        int so = row * LP + g * 8;
        *(uint2*)&sAh[so]     = make_uint2(vh.x, vh.y);
        *(uint2*)&sAh[so + 4] = make_uint2(vh.z, vh.w);
        *(uint2*)&sAl[so]     = make_uint2(vl.x, vl.y);
        *(uint2*)&sAl[so + 4] = make_uint2(vl.z, vl.w);
    }
    __syncthreads();
    if (tid < 64) { sAh[tid * LP] ^= 0x8000; sAl[tid * LP] ^= 0x8000; }  // negate time dim

    // per-lane fp32 d64 A value: this lane's S-row is c (within each rf tile)
    float a64r[2];
    #pragma unroll
    for (int rf = 0; rf < 2; ++rf)
        a64r[rf] = x64b[r0 + wr * 32 + rf * 16 + c];

    float rsum[2] = {0.0f, 0.0f};

    for (int tc = 0; tc < NS; tc += 128) {
        __syncthreads();
        for (int i = tid; i < 128 * 8; i += 512) {
            int row = i >> 3, g = i & 7;
            uint4 vh = *(const uint4*)&xhb[(size_t)(tc + row) * KX + g * 8];
            uint4 vl = *(const uint4*)&xlb[(size_t)(tc + row) * KX + g * 8];
            int so = row * LP + g * 8;
            *(uint2*)&sBh[so]     = make_uint2(vh.x, vh.y);
            *(uint2*)&sBh[so + 4] = make_uint2(vh.z, vh.w);
            *(uint2*)&sBl[so]     = make_uint2(vl.x, vl.y);
            *(uint2*)&sBl[so + 4] = make_uint2(vl.z, vl.w);
        }
        if (tid < 128) sB64[tid] = x64b[tc + tid];
        __syncthreads();

        f32x4 acc[2][2];
        #pragma unroll
        for (int rf = 0; rf < 2; ++rf)
            #pragma unroll
            for (int cf = 0; cf < 2; ++cf)
                #pragma unroll
                for (int j = 0; j < 4; ++j) acc[rf][cf][j] = 0.0f;

        #pragma unroll
        for (int kc = 0; kc < 2; ++kc) {
            const int koff = kc * 32 + q * 8;
            short8 ah[2], al[2], bh[2], bl[2];
            #pragma unroll
            for (int rf = 0; rf < 2; ++rf) {
                int ro = (wr * 32 + rf * 16 + c) * LP + koff;
                ah[rf] = ld8(&sAh[ro]);
                al[rf] = ld8(&sAl[ro]);
            }
            #pragma unroll
            for (int cf = 0; cf < 2; ++cf) {
                int co = (wc * 32 + cf * 16 + c) * LP + koff;
                bh[cf] = ld8(&sBh[co]);
                bl[cf] = ld8(&sBl[co]);
            }
            // swapped operands: D = S^T tile -> lane&15 = S-row, regs = 4 S-cols
            #pragma unroll
            for (int rf = 0; rf < 2; ++rf)
                #pragma unroll
                for (int cf = 0; cf < 2; ++cf) {
                    acc[rf][cf] = __builtin_amdgcn_mfma_f32_16x16x32_bf16(bh[cf], ah[rf], acc[rf][cf], 0, 0, 0);
                    acc[rf][cf] = __builtin_amdgcn_mfma_f32_16x16x32_bf16(bl[cf], ah[rf], acc[rf][cf], 0, 0, 0);
                    acc[rf][cf] = __builtin_amdgcn_mfma_f32_16x16x32_bf16(bh[cf], al[rf], acc[rf][cf], 0, 0, 0);
                }
        }

        // epilogue: + fp32 d64 term, acosh->e (rcp-free), packed ushort4 store
        #pragma unroll
        for (int rf = 0; rf < 2; ++rf) {
            const int row = wr * 32 + rf * 16 + c;
            #pragma unroll
            for (int cf = 0; cf < 2; ++cf) {
                float4 b64v = *(const float4*)&sB64[wc * 32 + cf * 16 + q * 4];
                float e4[4];
                #pragma unroll
                for (int j = 0; j < 4; ++j) {
                    float bj = (j == 0) ? b64v.x : (j == 1) ? b64v.y
                             : (j == 2) ? b64v.z : b64v.w;
                    float accf = acc[rf][cf][j] + a64r[rf] * bj;
                    float z = -accf;
                    z = fminf(fmaxf(z, 1.0000001f), 50.0f);
                    float s = __fsqrt_rn(z * z - 1.0f);
                    float e = fastT ? (z - s)                   // == 1/(z+s)
                                    : __expf(-__logf(z + s) * invT);
                    e4[j] = e;
                    rsum[rf] += e;
                }
                ushort4 pk = make_ushort4(
                    (ushort)__float2uint_rn(e4[0] * 65535.0f),
                    (ushort)__float2uint_rn(e4[1] * 65535.0f),
                    (ushort)__float2uint_rn(e4[2] * 65535.0f),
                    (ushort)__float2uint_rn(e4[3] * 65535.0f));
                *(ushort4*)&erow[(size_t)row * NS + tc + wc * 32 + cf * 16 + q * 4] = pk;
            }
        }
    }

    __syncthreads();                    // all frag reads done -> sBh reusable
    float* sSum = (float*)sBh;          // [4][64] aliases dead B tile
    #pragma unroll
    for (int rf = 0; rf < 2; ++rf) {
        float v = rsum[rf];
        v += __shfl_xor(v, 16, 64);     // sum the 4 q-lanes sharing this row
        v += __shfl_xor(v, 32, 64);
        if (q == 0) sSum[wc * 64 + wr * 32 + rf * 16 + c] = v;
    }
    __syncthreads();
    if (tid < 64)
        invb[(size_t)b * NS + r0 + tid] =
            1.0f / (sSum[tid] + sSum[64 + tid] + sSum[128 + tid] + sSum[192 + tid]);
}

// ---------------------------------------------------------------------------
// k2u (r14-proven): per (batch, 32-row block): T14-prefetched u16 E + V^T
// regs; phase 1 = unpack*inv -> pure float4 attn store + P bf16 hi/lo split
// to LDS + V^T ds_write; PV = 2-product MFMA. LDS 40960 B -> 4 blocks/CU.
// ---------------------------------------------------------------------------
__global__ __launch_bounds__(256, 4)
void k2u_pv(const ushort* __restrict__ eg, const ushort* __restrict__ vthi,
            const float* __restrict__ invb, float* __restrict__ attn,
            float* __restrict__ out)
{
    __shared__ __align__(16) char smem[40960];
    ushort* sAh = (ushort*)smem;                  // 32*136 u16 [0, 8704)
    ushort* sAl = sAh + 32 * 136;                 // [8704, 17408)
    ushort* sVh = sAl + 32 * 136;                 // 80*136 [17408, 39168)
    float*  sInvL = (float*)(smem + 39168);       // 128 B [39168, 39296)
    float*  sRed = (float*)smem;                  // 40960 B, post-loop only

    const int tid = threadIdx.x;
    // XCD swizzle: dispatch d -> logical f = (d%8)*64 + d/8 (bijective, 512%8==0)
    const int f  = (blockIdx.x & 7) * 64 + (blockIdx.x >> 3);
    const int b  = f >> 6;
    const int r0 = (f & 63) * 32;
    const int lane = tid & 63;
    const int wk = tid >> 6;          // k-slice 0..3 within each 128-chunk

    if (tid < 32) sInvL[tid] = invb[(size_t)b * NS + r0 + tid] * (1.0f / 65535.0f);

    const ushort* erow = eg + ((size_t)b * NS + r0) * NS;
    float* arow = attn + ((size_t)b * NS + r0) * NS;
    const ushort* vh = vthi + (size_t)b * VD * NS;

    short8 ereg[2];
    short8 vregh[5];
    auto loadE = [&](int kt) {
        #pragma unroll
        for (int rep = 0; rep < 2; ++rep) {
            int idx = tid + rep * 256;          // 512 = 32 rows x 16 col8-groups
            int row = idx >> 4, c8 = idx & 15;
            ereg[rep] = *(const short8*)&erow[(size_t)row * NS + kt + c8 * 8];
        }
    };
    auto loadV = [&](int kt) {
        #pragma unroll
        for (int rep = 0; rep < 5; ++rep) {
            int i = tid + rep * 256;
            int d = i >> 4, c8 = i & 15;
            vregh[rep] = *(const short8*)&vh[(size_t)d * NS + kt + c8 * 8];
        }
    };

    f32x4 acc[2][5];
    #pragma unroll
    for (int rf = 0; rf < 2; ++rf)
        #pragma unroll
        for (int ff = 0; ff < 5; ++ff)
            #pragma unroll
            for (int j = 0; j < 4; ++j) acc[rf][ff][j] = 0.0f;

    loadE(0);
    loadV(0);
    __syncthreads();

    for (int kt = 0; kt < NS; kt += 128) {
        // phase 1: unpack u16 -> en, pure float4 attn store, bf16 split to sA
        #pragma unroll
        for (int rep = 0; rep < 2; ++rep) {
            int idx = tid + rep * 256;
            int row = idx >> 4, c8 = idx & 15;
            float inv2 = sInvL[row];
            float en[8];
            #pragma unroll
            for (int i = 0; i < 8; ++i)
                en[i] = (float)(ushort)ereg[rep][i] * inv2;
            float4 fa = {en[0], en[1], en[2], en[3]};
            float4 fb = {en[4], en[5], en[6], en[7]};
            *(float4*)&arow[(size_t)row * NS + kt + c8 * 8]     = fa;
            *(float4*)&arow[(size_t)row * NS + kt + c8 * 8 + 4] = fb;
            ushort h[8], l[8];
            #pragma unroll
            for (int i = 0; i < 8; ++i) {
                h[i] = f2bf(en[i]);
                l[i] = f2bf(en[i] - bf2f(h[i]));
            }
            int so = row * 136 + c8 * 8;
            *(ushort4*)&sAh[so]     = make_ushort4(h[0], h[1], h[2], h[3]);
            *(ushort4*)&sAh[so + 4] = make_ushort4(h[4], h[5], h[6], h[7]);
            *(ushort4*)&sAl[so]     = make_ushort4(l[0], l[1], l[2], l[3]);
            *(ushort4*)&sAl[so + 4] = make_ushort4(l[4], l[5], l[6], l[7]);
        }
        #pragma unroll
        for (int rep = 0; rep < 5; ++rep) {
            int i = tid + rep * 256;
            int d = i >> 4, c8 = i & 15;
            *(short8*)&sVh[d * 136 + c8 * 8] = vregh[rep];
        }
        __syncthreads();

        if (kt + 128 < NS) { loadE(kt + 128); loadV(kt + 128); }

        const int koff = wk * 32 + (lane >> 4) * 8;
        short8 ah[2], al[2];
        #pragma unroll
        for (int rf = 0; rf < 2; ++rf) {
            int ro = (rf * 16 + (lane & 15)) * 136 + koff;
            ah[rf] = *(const short8*)&sAh[ro];
            al[rf] = *(const short8*)&sAl[ro];
        }
        #pragma unroll
        for (int ff = 0; ff < 5; ++ff) {
            short8 bh = *(const short8*)&sVh[(ff * 16 + (lane & 15)) * 136 + koff];
            #pragma unroll
            for (int rf = 0; rf < 2; ++rf) {
                acc[rf][ff] = __builtin_amdgcn_mfma_f32_16x16x32_bf16(ah[rf], bh, acc[rf][ff], 0, 0, 0);
                acc[rf][ff] = __builtin_amdgcn_mfma_f32_16x16x32_bf16(al[rf], bh, acc[rf][ff], 0, 0, 0);
            }
        }
        __syncthreads();
    }

    // k-slice partials -> sRed (aliases all staging), reduce, write out
    #pragma unroll
    for (int rf = 0; rf < 2; ++rf)
        #pragma unroll
        for (int ff = 0; ff < 5; ++ff)
            #pragma unroll
            for (int j = 0; j < 4; ++j) {
                int r = rf * 16 + (lane >> 4) * 4 + j;
                int d = ff * 16 + (lane & 15);
                sRed[((size_t)wk * 32 + r) * 80 + d] = acc[rf][ff][j];
            }
    __syncthreads();
    for (int i = tid; i < 32 * 80; i += 256) {
        int r = i / 80, d = i - r * 80;
        float s = sRed[(size_t)r * 80 + d] + sRed[(size_t)(32 + r) * 80 + d]
                + sRed[(size_t)(64 + r) * 80 + d] + sRed[(size_t)(96 + r) * 80 + d];
        if (d < ND) out[((size_t)b * NS + r0 + r) * ND + d] = s;
    }
}

extern "C" void kernel_launch(void* const* d_in, const int* in_sizes, int n_in,
                              void* d_out, int out_size, void* d_ws, size_t ws_size,
                              hipStream_t stream) {
    const float* x      = (const float*)d_in[0];
    const float* values = (const float*)d_in[1];
    const float* temp   = (const float*)d_in[2];

    float* out  = (float*)d_out;
    float* attn = out + OUTSZ;

    ushort* xhi  = (ushort*)d_ws;
    ushort* xlo  = xhi + CONVN;
    ushort* vthi = xlo + CONVN;
    float*  x64  = (float*)(vthi + VTN);
    float*  invb = x64 + (size_t)NB * NS;
    ushort* eg   = (ushort*)(invb + (size_t)NB * NS);

    k0_convert<<<(NB * NS * 8) / 256, 256, 0, stream>>>(x, xhi, xlo, x64);
    k0v_transpose<<<dim3(NS / 32, NB), 256, 0, stream>>>(values, vthi);

    k1u_scores<<<256, 512, 0, stream>>>(xhi, xlo, x64, temp, eg, invb);
    k2u_pv<<<512, 256, 0, stream>>>(eg, vthi, invb, attn, out);
}